// Round 1
// baseline (1420.644 us; speedup 1.0000x reference)
//
#include <hip/hip_runtime.h>
#include <hip/hip_bf16.h>

#define DEV_INLINE __device__ __forceinline__

constexpr int cS0 = 200000, cD0 = 40000, cD1 = 8192;
constexpr int cE0 = 640000, cE1 = 131072;
constexpr int cDIN = 256, cDH = 512, cDOUT = 256;

DEV_INLINE float bf2f(unsigned short u) {
    union { unsigned int i; float f; } x; x.i = ((unsigned int)u) << 16; return x.f;
}
DEV_INLINE unsigned short f2bf(float f) {
    union { float f; unsigned int i; } x; x.f = f;
    unsigned int r = x.i + 0x7FFF + ((x.i >> 16) & 1);
    return (unsigned short)(r >> 16);
}

// ---------------- CSR build ----------------

__global__ void k_deg(const int* __restrict__ dst, int E, int* __restrict__ deg) {
    int i = blockIdx.x * blockDim.x + threadIdx.x;
    if (i < E) atomicAdd(&deg[dst[i]], 1);
}

__global__ void k_scan(const int* __restrict__ deg, int* __restrict__ off, int n) {
    __shared__ int buf[1024];
    __shared__ int carry_s;
    int t = threadIdx.x;
    if (t == 0) carry_s = 0;
    __syncthreads();
    for (int base = 0; base < n; base += 1024) {
        int i = base + t;
        int v = (i < n) ? deg[i] : 0;
        buf[t] = v;
        __syncthreads();
        for (int o = 1; o < 1024; o <<= 1) {
            int tv = (t >= o) ? buf[t - o] : 0;
            __syncthreads();
            buf[t] += tv;
            __syncthreads();
        }
        int c0 = carry_s;
        if (i < n) off[i] = c0 + buf[t] - v;   // exclusive
        __syncthreads();
        if (t == 1023) carry_s = c0 + buf[1023];
        __syncthreads();
    }
    if (t == 0) off[n] = carry_s;
}

__global__ void k_fill(const int* __restrict__ src, const int* __restrict__ dst, int E,
                       const int* __restrict__ off, int* __restrict__ cur,
                       int* __restrict__ csr) {
    int i = blockIdx.x * blockDim.x + threadIdx.x;
    if (i < E) {
        int d = dst[i];
        int p = atomicAdd(&cur[d], 1);
        csr[off[d] + p] = src[i];
    }
}

// ---------------- neighbor aggregation (sum; mean scale applied in GEMM) ----------------
// one wave per dst node; lane covers K/64 contiguous elements

template <int K, bool SRC_BF16>
__global__ __launch_bounds__(256) void k_agg(const void* __restrict__ xsrc_v,
                                             const int* __restrict__ off,
                                             const int* __restrict__ csr,
                                             float* __restrict__ agg, int ndst) {
    constexpr int VEC = K / 64;
    int lane = threadIdx.x & 63;
    int d = blockIdx.x * 4 + (threadIdx.x >> 6);
    if (d >= ndst) return;
    float acc[VEC];
#pragma unroll
    for (int i = 0; i < VEC; i++) acc[i] = 0.f;
    int p0 = off[d], p1 = off[d + 1];
    if constexpr (!SRC_BF16) {
        const float* xs = (const float*)xsrc_v;
        for (int p = p0; p < p1; p++) {
            int s = csr[p];
            float4 v = ((const float4*)(xs + (size_t)s * K))[lane];
            acc[0] += v.x; acc[1] += v.y; acc[2] += v.z; acc[3] += v.w;
        }
    } else {
        const unsigned short* xs = (const unsigned short*)xsrc_v;
        for (int p = p0; p < p1; p++) {
            int s = csr[p];
            int4 v = ((const int4*)(xs + (size_t)s * K))[lane];
            const unsigned short* u = (const unsigned short*)&v;
#pragma unroll
            for (int i = 0; i < 8; i++) acc[i] += bf2f(u[i]);
        }
    }
    float* out = agg + (size_t)d * K + (size_t)lane * VEC;
#pragma unroll
    for (int i = 0; i < VEC; i += 4)
        *(float4*)(out + i) = make_float4(acc[i], acc[i + 1], acc[i + 2], acc[i + 3]);
}

// ---------------- fused SAGE GEMM ----------------
// out[m,n] = act( Aself[m,:]@Bself[:,n] + (Aagg[m,:]*sc[m])@Bneigh[:,n] + bias[n] )
// BM=64, BN=128, 256 threads, 4x8 register tile, fp32 VALU.

template <int K, int N, bool SELF_BF16, bool OUT_BF16, bool RELU>
__global__ __launch_bounds__(256) void k_gemm(const void* __restrict__ aself_v,
                                              const float* __restrict__ aagg,
                                              const int* __restrict__ off,
                                              const float* __restrict__ bself,
                                              const float* __restrict__ bneigh,
                                              const float* __restrict__ bias,
                                              void* __restrict__ out_v, int M) {
    constexpr int BM = 64, BN = 128, KS = 16;
    __shared__ float As[KS][BM];
    __shared__ float Bs[KS][BN];
    __shared__ float sc[BM];
    const int tiles_n = N / BN;
    int tm = blockIdx.x / tiles_n, tn = blockIdx.x % tiles_n;
    int m0 = tm * BM, n0 = tn * BN;
    int t = threadIdx.x;
    int ty = t >> 4, tx = t & 15;

    if (t < BM) {
        int d = m0 + t;
        int dg = off[d + 1] - off[d];
        sc[t] = 1.0f / (float)(dg > 1 ? dg : 1);
    }

    float acc[4][8];
#pragma unroll
    for (int i = 0; i < 4; i++)
#pragma unroll
        for (int j = 0; j < 8; j++) acc[i][j] = 0.f;

    int ar = t >> 2, ac = (t & 3) * 4;   // A tile: row, k-offset (loads 4 floats)
    int bk = t >> 4, bn = (t & 15) * 8;  // B tile: k-row, col-offset (loads 8 floats)

    for (int p = 0; p < 2; p++) {
        const float* B = p ? bneigh : bself;
        for (int k0 = 0; k0 < K; k0 += KS) {
            float av[4];
            if (p == 0) {
                if constexpr (SELF_BF16) {
                    const unsigned short* ap =
                        (const unsigned short*)aself_v + (size_t)(m0 + ar) * K + k0 + ac;
                    ushort4 u = *(const ushort4*)ap;
                    av[0] = bf2f(u.x); av[1] = bf2f(u.y); av[2] = bf2f(u.z); av[3] = bf2f(u.w);
                } else {
                    const float* ap = (const float*)aself_v + (size_t)(m0 + ar) * K + k0 + ac;
                    float4 v = *(const float4*)ap;
                    av[0] = v.x; av[1] = v.y; av[2] = v.z; av[3] = v.w;
                }
            } else {
                const float* ap = aagg + (size_t)(m0 + ar) * K + k0 + ac;
                float4 v = *(const float4*)ap;
                float s = sc[ar];  // written at kernel start; phase 1 runs after many barriers
                av[0] = v.x * s; av[1] = v.y * s; av[2] = v.z * s; av[3] = v.w * s;
            }
            const float* bp = B + (size_t)(k0 + bk) * N + n0 + bn;
            float4 b0 = *(const float4*)bp;
            float4 b1 = *(const float4*)(bp + 4);

            __syncthreads();  // previous step's compute done before overwrite
            As[ac + 0][ar] = av[0];
            As[ac + 1][ar] = av[1];
            As[ac + 2][ar] = av[2];
            As[ac + 3][ar] = av[3];
            *(float4*)&Bs[bk][bn] = b0;
            *(float4*)&Bs[bk][bn + 4] = b1;
            __syncthreads();

#pragma unroll
            for (int kk = 0; kk < KS; kk++) {
                float a0 = As[kk][ty * 4 + 0], a1 = As[kk][ty * 4 + 1];
                float a2 = As[kk][ty * 4 + 2], a3 = As[kk][ty * 4 + 3];
                float b[8];
#pragma unroll
                for (int j = 0; j < 8; j++) b[j] = Bs[kk][tx * 8 + j];
#pragma unroll
                for (int j = 0; j < 8; j++) {
                    acc[0][j] += a0 * b[j];
                    acc[1][j] += a1 * b[j];
                    acc[2][j] += a2 * b[j];
                    acc[3][j] += a3 * b[j];
                }
            }
        }
    }

    float bv[8];
#pragma unroll
    for (int j = 0; j < 8; j++) bv[j] = bias[n0 + tx * 8 + j];

    if constexpr (OUT_BF16) {
        unsigned short* out = (unsigned short*)out_v;
#pragma unroll
        for (int i = 0; i < 4; i++) {
            union { unsigned short us[8]; uint4 v; } pk;
#pragma unroll
            for (int j = 0; j < 8; j++) {
                float v = acc[i][j] + bv[j];
                if (RELU) v = fmaxf(v, 0.f);
                pk.us[j] = f2bf(v);
            }
            *(uint4*)&out[(size_t)(m0 + ty * 4 + i) * N + n0 + tx * 8] = pk.v;
        }
    } else {
        float* out = (float*)out_v;
#pragma unroll
        for (int i = 0; i < 4; i++) {
            float o[8];
#pragma unroll
            for (int j = 0; j < 8; j++) {
                float v = acc[i][j] + bv[j];
                if (RELU) v = fmaxf(v, 0.f);
                o[j] = v;
            }
            float* op = out + (size_t)(m0 + ty * 4 + i) * N + n0 + tx * 8;
            *(float4*)op = make_float4(o[0], o[1], o[2], o[3]);
            *(float4*)(op + 4) = make_float4(o[4], o[5], o[6], o[7]);
        }
    }
}

// ---------------- launch ----------------

extern "C" void kernel_launch(void* const* d_in, const int* in_sizes, int n_in,
                              void* d_out, int out_size, void* d_ws, size_t ws_size,
                              hipStream_t stream) {
    const float* x_user  = (const float*)d_in[0];
    const float* x_movie = (const float*)d_in[1];
    const float* W1r_n = (const float*)d_in[2];
    const float* W1r_s = (const float*)d_in[3];
    const float* b1r   = (const float*)d_in[4];
    const float* W1b_n = (const float*)d_in[5];
    const float* W1b_s = (const float*)d_in[6];
    const float* b1b   = (const float*)d_in[7];
    const float* W2r_n = (const float*)d_in[8];
    const float* W2r_s = (const float*)d_in[9];
    const float* b2r   = (const float*)d_in[10];
    const float* W2b_n = (const float*)d_in[11];
    const float* W2b_s = (const float*)d_in[12];
    const float* b2b   = (const float*)d_in[13];
    const int* e0r_src = (const int*)d_in[14];
    const int* e0r_dst = (const int*)d_in[15];
    const int* e0b_src = (const int*)d_in[16];
    const int* e0b_dst = (const int*)d_in[17];
    const int* e1r_src = (const int*)d_in[18];
    const int* e1r_dst = (const int*)d_in[19];
    const int* e1b_src = (const int*)d_in[20];
    const int* e1b_dst = (const int*)d_in[21];

    // workspace layout
    char* w = (char*)d_ws;
    size_t need = 0;
    unsigned short* h1m = (unsigned short*)(w + need); need += (size_t)cD0 * cDH * 2;  // 40.96 MB
    unsigned short* h1u = (unsigned short*)(w + need); need += (size_t)cD0 * cDH * 2;  // 40.96 MB
    float* agg = (float*)(w + need); need += (size_t)cD0 * cDIN * 4;                   // 40.96 MB (also fits D1*DH)
    int* deg = (int*)(w + need); need += 40064 * 4;
    int* off = (int*)(w + need); need += 40064 * 4;
    int* cur = (int*)(w + need); need += 40064 * 4;
    int* csr = (int*)(w + need); need += (size_t)cE0 * 4;                              // 2.56 MB
    if (ws_size < need) return;  // visible failure instead of OOB corruption

    float* out_u2 = (float*)d_out;
    float* out_m2 = (float*)d_out + (size_t)cD1 * cDOUT;

    auto build = [&](const int* esrc, const int* edst, int E, int ndst) {
        hipMemsetAsync(deg, 0, (size_t)ndst * sizeof(int), stream);
        k_deg<<<(E + 255) / 256, 256, 0, stream>>>(edst, E, deg);
        k_scan<<<1, 1024, 0, stream>>>(deg, off, ndst);
        hipMemsetAsync(cur, 0, (size_t)ndst * sizeof(int), stream);
        k_fill<<<(E + 255) / 256, 256, 0, stream>>>(esrc, edst, E, off, cur, csr);
    };

    // ---- layer 1, relation 'rates' (src=user, dst=movie) -> m1 = h1m ----
    build(e0r_src, e0r_dst, cE0, cD0);
    k_agg<cDIN, false><<<cD0 / 4, 256, 0, stream>>>(x_user, off, csr, agg, cD0);
    k_gemm<cDIN, cDH, false, true, true><<<(cD0 / 64) * (cDH / 128), 256, 0, stream>>>(
        x_movie, agg, off, W1r_s, W1r_n, b1r, h1m, cD0);

    // ---- layer 1, relation 'rated_by' (src=movie, dst=user) -> u1 = h1u ----
    build(e0b_src, e0b_dst, cE0, cD0);
    k_agg<cDIN, false><<<cD0 / 4, 256, 0, stream>>>(x_movie, off, csr, agg, cD0);
    k_gemm<cDIN, cDH, false, true, true><<<(cD0 / 64) * (cDH / 128), 256, 0, stream>>>(
        x_user, agg, off, W1b_s, W1b_n, b1b, h1u, cD0);

    // ---- layer 2, 'rates' (src=u1, dst=m1[:D1]) -> m2 ----
    build(e1r_src, e1r_dst, cE1, cD1);
    k_agg<cDH, true><<<cD1 / 4, 256, 0, stream>>>(h1u, off, csr, agg, cD1);
    k_gemm<cDH, cDOUT, true, false, false><<<(cD1 / 64) * (cDOUT / 128), 256, 0, stream>>>(
        h1m, agg, off, W2r_s, W2r_n, b2r, out_m2, cD1);

    // ---- layer 2, 'rated_by' (src=m1, dst=u1[:D1]) -> u2 ----
    build(e1b_src, e1b_dst, cE1, cD1);
    k_agg<cDH, true><<<cD1 / 4, 256, 0, stream>>>(h1m, off, csr, agg, cD1);
    k_gemm<cDH, cDOUT, true, false, false><<<(cD1 / 64) * (cDOUT / 128), 256, 0, stream>>>(
        h1u, agg, off, W2b_s, W2b_n, b2b, out_u2, cD1);
}

// Round 2
// 816.235 us; speedup vs baseline: 1.7405x; 1.7405x over previous
//
#include <hip/hip_runtime.h>
#include <hip/hip_bf16.h>
#include <stdint.h>

#define DEV_INLINE __device__ __forceinline__

constexpr int cS0 = 200000, cD0 = 40000, cD1 = 8192;
constexpr int cE0 = 640000, cE1 = 131072;
constexpr int cDIN = 256, cDH = 512, cDOUT = 256;

typedef __attribute__((ext_vector_type(8))) short bf16x8_t;
typedef __attribute__((ext_vector_type(4))) float f32x4_t;

DEV_INLINE float bf2f(unsigned short u) {
    union { unsigned int i; float f; } x; x.i = ((unsigned int)u) << 16; return x.f;
}
DEV_INLINE unsigned short f2bf(float f) {
    union { float f; unsigned int i; } x; x.f = f;
    unsigned int r = x.i + 0x7FFF + ((x.i >> 16) & 1);
    return (unsigned short)(r >> 16);
}

DEV_INLINE void gload_lds16(const void* g, void* l) {
    __builtin_amdgcn_global_load_lds(
        (__attribute__((address_space(1))) void*)(uintptr_t)g,
        (__attribute__((address_space(3))) void*)(uintptr_t)l,
        16, 0, 0);
}

// ---------------- CSR build ----------------

__global__ void k_deg(const int* __restrict__ dst, int E, int* __restrict__ deg) {
    int i = blockIdx.x * blockDim.x + threadIdx.x;
    if (i < E) atomicAdd(&deg[dst[i]], 1);
}

__global__ void k_scan(const int* __restrict__ deg, int* __restrict__ off, int n) {
    __shared__ int buf[1024];
    __shared__ int carry_s;
    int t = threadIdx.x;
    if (t == 0) carry_s = 0;
    __syncthreads();
    for (int base = 0; base < n; base += 1024) {
        int i = base + t;
        int v = (i < n) ? deg[i] : 0;
        buf[t] = v;
        __syncthreads();
        for (int o = 1; o < 1024; o <<= 1) {
            int tv = (t >= o) ? buf[t - o] : 0;
            __syncthreads();
            buf[t] += tv;
            __syncthreads();
        }
        int c0 = carry_s;
        if (i < n) off[i] = c0 + buf[t] - v;   // exclusive
        __syncthreads();
        if (t == 1023) carry_s = c0 + buf[1023];
        __syncthreads();
    }
    if (t == 0) off[n] = carry_s;
}

__global__ void k_fill(const int* __restrict__ src, const int* __restrict__ dst, int E,
                       const int* __restrict__ off, int* __restrict__ cur,
                       int* __restrict__ csr) {
    int i = blockIdx.x * blockDim.x + threadIdx.x;
    if (i < E) {
        int d = dst[i];
        int p = atomicAdd(&cur[d], 1);
        csr[off[d] + p] = src[i];
    }
}

// ---------------- fp32 -> bf16 conversion ----------------

__global__ void k_cvt(const float* __restrict__ in, unsigned short* __restrict__ out, long n8) {
    long i = (long)blockIdx.x * 256 + threadIdx.x;
    if (i >= n8) return;
    const float4* p = (const float4*)(in + i * 8);
    float4 a = p[0], b = p[1];
    union { unsigned short us[8]; uint4 v; } pk;
    pk.us[0] = f2bf(a.x); pk.us[1] = f2bf(a.y); pk.us[2] = f2bf(a.z); pk.us[3] = f2bf(a.w);
    pk.us[4] = f2bf(b.x); pk.us[5] = f2bf(b.y); pk.us[6] = f2bf(b.z); pk.us[7] = f2bf(b.w);
    *(uint4*)(out + i * 8) = pk.v;
}

// W [K][N] fp32 -> Wt [N][K] bf16
__global__ void k_wt(const float* __restrict__ w, unsigned short* __restrict__ wt, int K, int N) {
    int idx = blockIdx.x * 256 + threadIdx.x;
    if (idx >= K * N) return;
    int n = idx / K, k = idx % K;
    wt[idx] = f2bf(w[(size_t)k * N + n]);
}

// ---------------- neighbor aggregation: mean, bf16 out ----------------
// one wave per dst node; lane covers K/64 contiguous elements

template <int K, bool SRC_BF16>
__global__ __launch_bounds__(256) void k_agg(const void* __restrict__ xsrc_v,
                                             const int* __restrict__ off,
                                             const int* __restrict__ csr,
                                             unsigned short* __restrict__ agg, int ndst) {
    constexpr int VEC = K / 64;   // 4 or 8
    int lane = threadIdx.x & 63;
    int d = blockIdx.x * 4 + (threadIdx.x >> 6);
    if (d >= ndst) return;
    float acc[VEC];
#pragma unroll
    for (int i = 0; i < VEC; i++) acc[i] = 0.f;
    int p0 = off[d], p1 = off[d + 1];
    if constexpr (SRC_BF16) {
        const unsigned short* xs = (const unsigned short*)xsrc_v;
        for (int p = p0; p < p1; p++) {
            int s = csr[p];
            if constexpr (VEC == 4) {
                uint2 v = ((const uint2*)(xs + (size_t)s * K))[lane];
                const unsigned short* u = (const unsigned short*)&v;
#pragma unroll
                for (int i = 0; i < 4; i++) acc[i] += bf2f(u[i]);
            } else {
                uint4 v = ((const uint4*)(xs + (size_t)s * K))[lane];
                const unsigned short* u = (const unsigned short*)&v;
#pragma unroll
                for (int i = 0; i < 8; i++) acc[i] += bf2f(u[i]);
            }
        }
    } else {
        const float* xs = (const float*)xsrc_v;
        for (int p = p0; p < p1; p++) {
            int s = csr[p];
#pragma unroll
            for (int i = 0; i < VEC / 4; ++i) {
                float4 v = ((const float4*)(xs + (size_t)s * K))[lane * (VEC / 4) + i];
                acc[i * 4 + 0] += v.x; acc[i * 4 + 1] += v.y;
                acc[i * 4 + 2] += v.z; acc[i * 4 + 3] += v.w;
            }
        }
    }
    int dg = p1 - p0;
    float sc = 1.0f / (float)(dg > 1 ? dg : 1);
    union { unsigned short us[VEC]; uint2 v2; uint4 v4; } pk;
#pragma unroll
    for (int i = 0; i < VEC; i++) pk.us[i] = f2bf(acc[i] * sc);
    unsigned short* out = agg + (size_t)d * K + (size_t)lane * VEC;
    if constexpr (VEC == 4) *(uint2*)out = pk.v2;
    else                    *(uint4*)out = pk.v4;
}

// ---------------- fused SAGE GEMM (MFMA bf16) ----------------
// out[M,N] = act( Aself@Wself + Aagg@Wneigh + bias ), K concat as 2 segments.
// A*: [M][KSEG] bf16 row-major. Wt*: [N][KSEG] bf16 row-major (transposed weights).
// BM=64 BN=128 BK=64, 4 waves in 2x2, wave tile 32x64 (2x4 16x16 frags).
// LDS tiles row-major 64 bf16/row (128B), 16B-chunk XOR swizzle: phys = logical ^ (row&7),
// realized by pre-swizzling the global source address (LDS dest linear for global_load_lds).

template <int KSEG, int N, bool OUT_BF16, bool RELU>
__global__ __launch_bounds__(256) void k_gemm(
    const unsigned short* __restrict__ aself, const unsigned short* __restrict__ aagg,
    const unsigned short* __restrict__ bts, const unsigned short* __restrict__ btn,
    const float* __restrict__ bias, void* __restrict__ out_v)
{
    constexpr int BM = 64, BN = 128, BK = 64;
    constexpr int H = KSEG / BK, NSTEP = 2 * H;
    __shared__ __align__(16) unsigned short As[2][BM * BK];
    __shared__ __align__(16) unsigned short Bs[2][BN * BK];

    const int tiles_n = N / BN;
    const int m0 = (blockIdx.x / tiles_n) * BM;
    const int n0 = (blockIdx.x % tiles_n) * BN;
    const int t = threadIdx.x, lane = t & 63, wave = t >> 6;
    const int wr = wave >> 1, wc = wave & 1;
    const int l15 = lane & 15, l4 = lane >> 4;

    f32x4_t acc[2][4];
    const f32x4_t zero = {0.f, 0.f, 0.f, 0.f};
#pragma unroll
    for (int i = 0; i < 2; i++)
#pragma unroll
        for (int j = 0; j < 4; j++) acc[i][j] = zero;

    auto stage = [&](int buf, int s) {
        const int seg = (s >= H) ? 1 : 0;
        const int k0 = (s - seg * H) * BK;
        const unsigned short* A = seg ? aagg : aself;
        const unsigned short* B = seg ? btn : bts;
#pragma unroll
        for (int it = 0; it < 2; ++it) {            // A: 64 rows x 128B = 512 chunks
            int c = it * 256 + wave * 64 + lane;
            int row = c >> 3;
            int lch = (c & 7) ^ (row & 7);
            gload_lds16(A + (size_t)(m0 + row) * KSEG + k0 + lch * 8,
                        (char*)&As[buf][0] + (it * 256 + wave * 64) * 16);
        }
#pragma unroll
        for (int it = 0; it < 4; ++it) {            // B: 128 rows x 128B = 1024 chunks
            int c = it * 256 + wave * 64 + lane;
            int row = c >> 3;
            int lch = (c & 7) ^ (row & 7);
            gload_lds16(B + (size_t)(n0 + row) * KSEG + k0 + lch * 8,
                        (char*)&Bs[buf][0] + (it * 256 + wave * 64) * 16);
        }
    };

    int cur = 0;
    stage(0, 0);
    for (int s = 0; s < NSTEP; ++s) {
        __syncthreads();                  // drains vmcnt -> buf[cur] ready; prev reads done
        if (s + 1 < NSTEP) stage(cur ^ 1, s + 1);
        const char* Ab = (const char*)&As[cur][0];
        const char* Bb = (const char*)&Bs[cur][0];
        bf16x8_t a[2][2], b[4][2];
#pragma unroll
        for (int fm = 0; fm < 2; ++fm) {
            int row = wr * 32 + fm * 16 + l15;
#pragma unroll
            for (int ks = 0; ks < 2; ++ks) {
                int pc = (ks * 4 + l4) ^ (row & 7);
                a[fm][ks] = *(const bf16x8_t*)(Ab + row * 128 + pc * 16);
            }
        }
#pragma unroll
        for (int fn = 0; fn < 4; ++fn) {
            int row = wc * 64 + fn * 16 + l15;
#pragma unroll
            for (int ks = 0; ks < 2; ++ks) {
                int pc = (ks * 4 + l4) ^ (row & 7);
                b[fn][ks] = *(const bf16x8_t*)(Bb + row * 128 + pc * 16);
            }
        }
#pragma unroll
        for (int ks = 0; ks < 2; ++ks)
#pragma unroll
            for (int fm = 0; fm < 2; ++fm)
#pragma unroll
                for (int fn = 0; fn < 4; ++fn)
                    acc[fm][fn] = __builtin_amdgcn_mfma_f32_16x16x32_bf16(
                        a[fm][ks], b[fn][ks], acc[fm][fn], 0, 0, 0);
        cur ^= 1;
    }

#pragma unroll
    for (int fm = 0; fm < 2; ++fm) {
#pragma unroll
        for (int fn = 0; fn < 4; ++fn) {
            int col = n0 + wc * 64 + fn * 16 + l15;
            float bb = bias[col];
            f32x4_t v = acc[fm][fn];
#pragma unroll
            for (int r = 0; r < 4; ++r) {
                int rowg = m0 + wr * 32 + fm * 16 + l4 * 4 + r;
                float o = v[r] + bb;
                if (RELU) o = fmaxf(o, 0.f);
                if constexpr (OUT_BF16)
                    ((unsigned short*)out_v)[(size_t)rowg * N + col] = f2bf(o);
                else
                    ((float*)out_v)[(size_t)rowg * N + col] = o;
            }
        }
    }
}

// ---------------- launch ----------------

extern "C" void kernel_launch(void* const* d_in, const int* in_sizes, int n_in,
                              void* d_out, int out_size, void* d_ws, size_t ws_size,
                              hipStream_t stream) {
    const float* x_user  = (const float*)d_in[0];
    const float* x_movie = (const float*)d_in[1];
    const float* W1r_n = (const float*)d_in[2];
    const float* W1r_s = (const float*)d_in[3];
    const float* b1r   = (const float*)d_in[4];
    const float* W1b_n = (const float*)d_in[5];
    const float* W1b_s = (const float*)d_in[6];
    const float* b1b   = (const float*)d_in[7];
    const float* W2r_n = (const float*)d_in[8];
    const float* W2r_s = (const float*)d_in[9];
    const float* b2r   = (const float*)d_in[10];
    const float* W2b_n = (const float*)d_in[11];
    const float* W2b_s = (const float*)d_in[12];
    const float* b2b   = (const float*)d_in[13];
    const int* e0r_src = (const int*)d_in[14];
    const int* e0r_dst = (const int*)d_in[15];
    const int* e0b_src = (const int*)d_in[16];
    const int* e0b_dst = (const int*)d_in[17];
    const int* e1r_src = (const int*)d_in[18];
    const int* e1r_dst = (const int*)d_in[19];
    const int* e1b_src = (const int*)d_in[20];
    const int* e1b_dst = (const int*)d_in[21];

    // ---- workspace layout ----
    char* w = (char*)d_ws;
    size_t o = 0;
    auto take = [&](size_t bytes) -> void* {
        void* p = w + o; o += (bytes + 255) & ~(size_t)255; return p;
    };
    unsigned short* h1m  = (unsigned short*)take((size_t)cD0 * cDH * 2);
    unsigned short* h1u  = (unsigned short*)take((size_t)cD0 * cDH * 2);
    unsigned short* aggb = (unsigned short*)take((size_t)cD0 * cDIN * 2);  // >= D1*DH*2
    unsigned short* wt   = (unsigned short*)take((size_t)8 * 131072 * 2);
    int* deg  = (int*)take((size_t)(cD0 + 64) * 4);
    int* offb = (int*)take((size_t)(cD0 + 64) * 4);
    int* cur  = (int*)take((size_t)(cD0 + 64) * 4);
    int* csr  = (int*)take((size_t)cE0 * 4);
    size_t base = o;
    bool full = (ws_size >= base + 2 * ((size_t)cS0 * cDIN * 2 + 256) + 256);
    size_t xrows = full ? (size_t)cS0 : (size_t)cD0;
    unsigned short* xub = (unsigned short*)take(xrows * cDIN * 2);
    unsigned short* xmb = (unsigned short*)take(xrows * cDIN * 2);
    if (ws_size < o) return;  // insufficient workspace: fail visibly

    float* out_u2 = (float*)d_out;
    float* out_m2 = (float*)d_out + (size_t)cD1 * cDOUT;

    // ---- bf16 conversions ----
    long n8 = (long)xrows * cDIN / 8;
    k_cvt<<<(unsigned)(n8 / 256), 256, 0, stream>>>(x_user, xub, n8);
    k_cvt<<<(unsigned)(n8 / 256), 256, 0, stream>>>(x_movie, xmb, n8);
    auto WT = [&](const float* W, int slot, int K, int N) {
        k_wt<<<(K * N + 255) / 256, 256, 0, stream>>>(W, wt + (size_t)slot * 131072, K, N);
    };
    WT(W1r_s, 0, cDIN, cDH); WT(W1r_n, 1, cDIN, cDH);
    WT(W1b_s, 2, cDIN, cDH); WT(W1b_n, 3, cDIN, cDH);
    WT(W2r_s, 4, cDH, cDOUT); WT(W2r_n, 5, cDH, cDOUT);
    WT(W2b_s, 6, cDH, cDOUT); WT(W2b_n, 7, cDH, cDOUT);

    auto build = [&](const int* esrc, const int* edst, int E, int ndst) {
        hipMemsetAsync(deg, 0, (size_t)ndst * sizeof(int), stream);
        k_deg<<<(E + 255) / 256, 256, 0, stream>>>(edst, E, deg);
        k_scan<<<1, 1024, 0, stream>>>(deg, offb, ndst);
        hipMemsetAsync(cur, 0, (size_t)ndst * sizeof(int), stream);
        k_fill<<<(E + 255) / 256, 256, 0, stream>>>(esrc, edst, E, offb, cur, csr);
    };

    // ---- layer 1, 'rates' (src=user, dst=movie) -> h1m ----
    build(e0r_src, e0r_dst, cE0, cD0);
    if (full) k_agg<cDIN, true ><<<cD0 / 4, 256, 0, stream>>>(xub, offb, csr, aggb, cD0);
    else      k_agg<cDIN, false><<<cD0 / 4, 256, 0, stream>>>(x_user, offb, csr, aggb, cD0);
    k_gemm<cDIN, cDH, true, true><<<(cD0 / 64) * (cDH / 128), 256, 0, stream>>>(
        xmb, aggb, wt + 0 * 131072, wt + 1 * 131072, b1r, h1m);

    // ---- layer 1, 'rated_by' (src=movie, dst=user) -> h1u ----
    build(e0b_src, e0b_dst, cE0, cD0);
    if (full) k_agg<cDIN, true ><<<cD0 / 4, 256, 0, stream>>>(xmb, offb, csr, aggb, cD0);
    else      k_agg<cDIN, false><<<cD0 / 4, 256, 0, stream>>>(x_movie, offb, csr, aggb, cD0);
    k_gemm<cDIN, cDH, true, true><<<(cD0 / 64) * (cDH / 128), 256, 0, stream>>>(
        xub, aggb, wt + 2 * 131072, wt + 3 * 131072, b1b, h1u);

    // ---- layer 2, 'rates' (src=u1, dst=m1[:D1]) -> m2 ----
    build(e1r_src, e1r_dst, cE1, cD1);
    k_agg<cDH, true><<<cD1 / 4, 256, 0, stream>>>(h1u, offb, csr, aggb, cD1);
    k_gemm<cDH, cDOUT, false, false><<<(cD1 / 64) * (cDOUT / 128), 256, 0, stream>>>(
        h1m, aggb, wt + 4 * 131072, wt + 5 * 131072, b2r, out_m2);

    // ---- layer 2, 'rated_by' (src=m1, dst=u1[:D1]) -> u2 ----
    build(e1b_src, e1b_dst, cE1, cD1);
    k_agg<cDH, true><<<cD1 / 4, 256, 0, stream>>>(h1m, offb, csr, aggb, cD1);
    k_gemm<cDH, cDOUT, false, false><<<(cD1 / 64) * (cDOUT / 128), 256, 0, stream>>>(
        h1u, aggb, wt + 6 * 131072, wt + 7 * 131072, b2b, out_u2);
}

// Round 3
// 564.401 us; speedup vs baseline: 2.5171x; 1.4462x over previous
//
#include <hip/hip_runtime.h>
#include <stdint.h>

#define DEV_INLINE __device__ __forceinline__

constexpr int cS0 = 200000, cD0 = 40000, cD1 = 8192;
constexpr int cE0 = 640000, cE1 = 131072;
constexpr int cDIN = 256, cDH = 512, cDOUT = 256;

// padded per-relation node-region sizes (multiples of 1024; D1 regions get +1024 so off[n] exists)
constexpr int P0 = 40960, P1 = 9216;
constexpr int NTOT = 2 * P0 + 2 * P1;   // 100352
constexpr int NBLK = NTOT / 1024;       // 98
constexpr int ETOT = 2 * cE0 + 2 * cE1; // 1542144

typedef __attribute__((ext_vector_type(8))) short bf16x8_t;
typedef __attribute__((ext_vector_type(4))) float f32x4_t;

DEV_INLINE float bf2f(unsigned short u) {
    union { unsigned int i; float f; } x; x.i = ((unsigned int)u) << 16; return x.f;
}
DEV_INLINE unsigned short f2bf(float f) {
    union { float f; unsigned int i; } x; x.f = f;
    unsigned int r = x.i + 0x7FFF + ((x.i >> 16) & 1);
    return (unsigned short)(r >> 16);
}

DEV_INLINE void gload_lds16(const void* g, void* l) {
    __builtin_amdgcn_global_load_lds(
        (__attribute__((address_space(1))) void*)(uintptr_t)g,
        (__attribute__((address_space(3))) void*)(uintptr_t)l,
        16, 0, 0);
}

// ---------------- fp32 -> bf16 conversion (both x tables, one kernel) ----------------

__global__ __launch_bounds__(256) void k_cvt_all(const float* __restrict__ a, const float* __restrict__ b,
                                                 unsigned short* __restrict__ oa, unsigned short* __restrict__ ob) {
    const long n8 = (long)cS0 * cDIN / 8;
    long i = (long)blockIdx.x * 256 + threadIdx.x;
    const float* in; unsigned short* out;
    if (i >= n8) { in = b; out = ob; i -= n8; } else { in = a; out = oa; }
    const float4* p = (const float4*)(in + i * 8);
    float4 u = p[0], v = p[1];
    union { unsigned short us[8]; uint4 q; } pk;
    pk.us[0] = f2bf(u.x); pk.us[1] = f2bf(u.y); pk.us[2] = f2bf(u.z); pk.us[3] = f2bf(u.w);
    pk.us[4] = f2bf(v.x); pk.us[5] = f2bf(v.y); pk.us[6] = f2bf(v.z); pk.us[7] = f2bf(v.w);
    *(uint4*)(out + i * 8) = pk.q;
}

// ---------------- all 8 weight transposes: W[K][N] fp32 -> Wt[N][K] bf16 ----------------

struct WPtrs { const float* w[8]; };

__global__ __launch_bounds__(256) void k_wt_all(WPtrs W, unsigned short* __restrict__ wt) {
    int idx = blockIdx.x * 256 + threadIdx.x;      // 8 * 131072 total
    int slot = idx >> 17, e = idx & 131071;
    int K = slot < 4 ? cDIN : cDH;
    int N = slot < 4 ? cDH : cDOUT;
    int n = e / K, k = e % K;
    wt[idx] = f2bf(W.w[slot][(size_t)k * N + n]);
}

// ---------------- CSR build over all 4 relations ----------------

__global__ __launch_bounds__(256) void k_deg_all(const int* __restrict__ d0, const int* __restrict__ d1,
                                                 const int* __restrict__ d2, const int* __restrict__ d3,
                                                 int* __restrict__ deg) {
    int i = blockIdx.x * 256 + threadIdx.x;
    if (i >= ETOT) return;
    const int* dp; int base, noff;
    if (i < cE0)               { dp = d0; base = 0;           noff = 0; }
    else if (i < 2 * cE0)      { dp = d1; base = cE0;         noff = P0; }
    else if (i < 2 * cE0 + cE1){ dp = d2; base = 2 * cE0;     noff = 2 * P0; }
    else                       { dp = d3; base = 2 * cE0 + cE1; noff = 2 * P0 + P1; }
    atomicAdd(&deg[noff + dp[i - base]], 1);
}

// per-1024-element block exclusive scan + block totals
__global__ __launch_bounds__(256) void k_scanA(const int* __restrict__ deg, int* __restrict__ off,
                                               int* __restrict__ btot) {
    __shared__ int buf[256];
    int t = threadIdx.x;
    long base = (long)blockIdx.x * 1024;
    int4 v = *(const int4*)(deg + base + t * 4);
    int s1 = v.x + v.y, s2 = s1 + v.z, ts = s2 + v.w;
    buf[t] = ts; __syncthreads();
    for (int o = 1; o < 256; o <<= 1) {
        int u = (t >= o) ? buf[t - o] : 0;
        __syncthreads(); buf[t] += u; __syncthreads();
    }
    int ex = buf[t] - ts;
    int4 w; w.x = ex; w.y = ex + v.x; w.z = ex + s1; w.w = ex + s2;
    *(int4*)(off + base + t * 4) = w;
    if (t == 255) btot[blockIdx.x] = buf[255];
}

// segmented exclusive scan of the 98 block totals (segments = 4 node regions)
__global__ void k_scanB(int* __restrict__ bt) {
    __shared__ int buf[128];
    __shared__ int seg[128];
    int t = threadIdx.x;
    int s = (t >= 89) ? 3 : (t >= 80) ? 2 : (t >= 40) ? 1 : 0;
    int v = (t < NBLK) ? bt[t] : 0;
    buf[t] = v; seg[t] = s; __syncthreads();
    for (int o = 1; o < 128; o <<= 1) {
        int u = 0;
        if (t >= o && seg[t - o] == s) u = buf[t - o];
        __syncthreads(); buf[t] += u; __syncthreads();
    }
    if (t < NBLK) bt[t] = buf[t] - v;   // exclusive within segment
}

__global__ __launch_bounds__(256) void k_scanC(int* __restrict__ off, const int* __restrict__ bt) {
    int t = threadIdx.x;
    long base = (long)blockIdx.x * 1024;
    int bo = bt[blockIdx.x];
    int4 v = *(int4*)(off + base + t * 4);
    v.x += bo; v.y += bo; v.z += bo; v.w += bo;
    *(int4*)(off + base + t * 4) = v;
}

__global__ __launch_bounds__(256) void k_fill_all(
    const int* __restrict__ s0, const int* __restrict__ d0, const int* __restrict__ s1, const int* __restrict__ d1,
    const int* __restrict__ s2, const int* __restrict__ d2, const int* __restrict__ s3, const int* __restrict__ d3,
    const int* __restrict__ off, int* __restrict__ cur, int* __restrict__ csr) {
    int i = blockIdx.x * 256 + threadIdx.x;
    if (i >= ETOT) return;
    const int* sp; const int* dp; int base, noff, cbase;
    if (i < cE0)               { sp = s0; dp = d0; base = 0;            noff = 0;           cbase = 0; }
    else if (i < 2 * cE0)      { sp = s1; dp = d1; base = cE0;          noff = P0;          cbase = cE0; }
    else if (i < 2 * cE0 + cE1){ sp = s2; dp = d2; base = 2 * cE0;      noff = 2 * P0;      cbase = 2 * cE0; }
    else                       { sp = s3; dp = d3; base = 2 * cE0 + cE1; noff = 2 * P0 + P1; cbase = 2 * cE0 + cE1; }
    int li = i - base;
    int d = dp[li];
    int p = atomicAdd(&cur[noff + d], 1);
    csr[cbase + off[noff + d] + p] = sp[li];
}

// ---------------- merged mean aggregation (2 relations per launch), bf16 in/out ----------------

template <int K>
__global__ __launch_bounds__(256) void k_agg2(
    const unsigned short* __restrict__ x0, const int* __restrict__ off0, const int* __restrict__ csr0,
    unsigned short* __restrict__ o0,
    const unsigned short* __restrict__ x1, const int* __restrict__ off1, const int* __restrict__ csr1,
    unsigned short* __restrict__ o1, int ndst) {
    constexpr int VEC = K / 64;   // 4 (K=256) or 8 (K=512)
    int nb = ndst / 4;
    int b = blockIdx.x;
    const unsigned short* xs; const int* off; const int* csr; unsigned short* out;
    if (b >= nb) { xs = x1; off = off1; csr = csr1; out = o1; b -= nb; }
    else         { xs = x0; off = off0; csr = csr0; out = o0; }
    int lane = threadIdx.x & 63;
    int d = b * 4 + (threadIdx.x >> 6);
    float acc[VEC];
#pragma unroll
    for (int i = 0; i < VEC; i++) acc[i] = 0.f;
    int p0 = off[d], p1 = off[d + 1];
    if constexpr (VEC == 4) {
        for (int p = p0; p < p1; p++) {
            int s = csr[p];
            uint2 v = ((const uint2*)(xs + (size_t)s * K))[lane];
            const unsigned short* u = (const unsigned short*)&v;
#pragma unroll
            for (int i = 0; i < 4; i++) acc[i] += bf2f(u[i]);
        }
    } else {
        for (int p = p0; p < p1; p++) {
            int s = csr[p];
            uint4 v = ((const uint4*)(xs + (size_t)s * K))[lane];
            const unsigned short* u = (const unsigned short*)&v;
#pragma unroll
            for (int i = 0; i < 8; i++) acc[i] += bf2f(u[i]);
        }
    }
    int dg = p1 - p0;
    float sc = 1.0f / (float)(dg > 1 ? dg : 1);
    union { unsigned short us[8]; uint2 v2; uint4 v4; } pk;
#pragma unroll
    for (int i = 0; i < VEC; i++) pk.us[i] = f2bf(acc[i] * sc);
    unsigned short* op = out + (size_t)d * K + (size_t)lane * VEC;
    if constexpr (VEC == 4) *(uint2*)op = pk.v2;
    else                    *(uint4*)op = pk.v4;
}

// ---------------- fused SAGE GEMM (MFMA bf16), 2 relations per launch ----------------
// out = act( Aself@Wself + Aagg@Wneigh + bias ); K concat as 2 segments of KSEG.
// BMxBN tile (BN=128), BK=64; 4 waves 2x2; wave tile (BM/2)x64.
// LDS rows of 64 bf16 (128B = 8 x 16B chunks); chunk-XOR swizzle phys = logical ^ (row&7),
// applied on the *global source* address (LDS dest stays linear for global_load_lds).

template <int BM, int KSEG, int N, bool OUT_BF16, bool RELU>
__global__ __launch_bounds__(256) void k_gemm2(
    const unsigned short* __restrict__ aself0, const unsigned short* __restrict__ aagg0,
    const unsigned short* __restrict__ bts0, const unsigned short* __restrict__ btn0,
    const float* __restrict__ bias0, void* __restrict__ out0,
    const unsigned short* __restrict__ aself1, const unsigned short* __restrict__ aagg1,
    const unsigned short* __restrict__ bts1, const unsigned short* __restrict__ btn1,
    const float* __restrict__ bias1, void* __restrict__ out1,
    int mtiles) {
    constexpr int BN = 128, BK = 64;
    constexpr int H = KSEG / BK, NSTEP = 2 * H;
    constexpr int WROWS = BM / 2, FM = WROWS / 16;   // frags per wave (row dim)
    constexpr int AIT = BM / 32;                     // A staging iterations
    __shared__ __align__(16) unsigned short As[2][BM * BK];
    __shared__ __align__(16) unsigned short Bs[2][BN * BK];

    const int tiles_n = N / BN;
    const int gpr = mtiles * tiles_n;
    int b = blockIdx.x;
    const unsigned short *aself, *aagg, *bts, *btn; const float* bias; void* out;
    if (b >= gpr) { b -= gpr; aself = aself1; aagg = aagg1; bts = bts1; btn = btn1; bias = bias1; out = out1; }
    else          {           aself = aself0; aagg = aagg0; bts = bts0; btn = btn0; bias = bias0; out = out0; }
    const int m0 = (b / tiles_n) * BM;
    const int n0 = (b % tiles_n) * BN;
    const int t = threadIdx.x, lane = t & 63, wave = t >> 6;
    const int wr = wave >> 1, wc = wave & 1;
    const int l15 = lane & 15, l4 = lane >> 4;

    f32x4_t acc[FM][4];
    const f32x4_t zero = {0.f, 0.f, 0.f, 0.f};
#pragma unroll
    for (int i = 0; i < FM; i++)
#pragma unroll
        for (int j = 0; j < 4; j++) acc[i][j] = zero;

    auto stage = [&](int buf, int s) {
        const int seg = (s >= H) ? 1 : 0;
        const int k0 = (s - seg * H) * BK;
        const unsigned short* A = seg ? aagg : aself;
        const unsigned short* B = seg ? btn : bts;
#pragma unroll
        for (int it = 0; it < AIT; ++it) {          // A: BM rows x 8 chunks
            int c = it * 256 + t;
            int row = c >> 3;
            int lch = (c & 7) ^ (row & 7);
            gload_lds16(A + (size_t)(m0 + row) * KSEG + k0 + lch * 8,
                        (char*)&As[buf][0] + (it * 256 + wave * 64) * 16);
        }
#pragma unroll
        for (int it = 0; it < 4; ++it) {            // B: 128 rows x 8 chunks
            int c = it * 256 + t;
            int row = c >> 3;
            int lch = (c & 7) ^ (row & 7);
            gload_lds16(B + (size_t)(n0 + row) * KSEG + k0 + lch * 8,
                        (char*)&Bs[buf][0] + (it * 256 + wave * 64) * 16);
        }
    };

    int cur = 0;
    stage(0, 0);
    for (int s = 0; s < NSTEP; ++s) {
        __syncthreads();                  // drains vmcnt -> buf[cur] staged; prior reads done
        if (s + 1 < NSTEP) stage(cur ^ 1, s + 1);
        const char* Ab = (const char*)&As[cur][0];
        const char* Bb = (const char*)&Bs[cur][0];
        bf16x8_t a[FM][2], bb[4][2];
#pragma unroll
        for (int fm = 0; fm < FM; ++fm) {
            int row = wr * WROWS + fm * 16 + l15;
#pragma unroll
            for (int ks = 0; ks < 2; ++ks) {
                int pc = (ks * 4 + l4) ^ (row & 7);
                a[fm][ks] = *(const bf16x8_t*)(Ab + row * 128 + pc * 16);
            }
        }
#pragma unroll
        for (int fn = 0; fn < 4; ++fn) {
            int row = wc * 64 + fn * 16 + l15;
#pragma unroll
            for (int ks = 0; ks < 2; ++ks) {
                int pc = (ks * 4 + l4) ^ (row & 7);
                bb[fn][ks] = *(const bf16x8_t*)(Bb + row * 128 + pc * 16);
            }
        }
#pragma unroll
        for (int ks = 0; ks < 2; ++ks)
#pragma unroll
            for (int fm = 0; fm < FM; ++fm)
#pragma unroll
                for (int fn = 0; fn < 4; ++fn)
                    acc[fm][fn] = __builtin_amdgcn_mfma_f32_16x16x32_bf16(
                        a[fm][ks], bb[fn][ks], acc[fm][fn], 0, 0, 0);
        cur ^= 1;
    }

#pragma unroll
    for (int fm = 0; fm < FM; ++fm) {
#pragma unroll
        for (int fn = 0; fn < 4; ++fn) {
            int col = n0 + wc * 64 + fn * 16 + l15;
            float bv = bias[col];
            f32x4_t v = acc[fm][fn];
#pragma unroll
            for (int r = 0; r < 4; ++r) {
                int rowg = m0 + wr * WROWS + fm * 16 + l4 * 4 + r;
                float o = v[r] + bv;
                if (RELU) o = fmaxf(o, 0.f);
                if constexpr (OUT_BF16)
                    ((unsigned short*)out)[(size_t)rowg * N + col] = f2bf(o);
                else
                    ((float*)out)[(size_t)rowg * N + col] = o;
            }
        }
    }
}

// ---------------- launch ----------------

extern "C" void kernel_launch(void* const* d_in, const int* in_sizes, int n_in,
                              void* d_out, int out_size, void* d_ws, size_t ws_size,
                              hipStream_t stream) {
    const float* x_user  = (const float*)d_in[0];
    const float* x_movie = (const float*)d_in[1];
    const float* W1r_n = (const float*)d_in[2];
    const float* W1r_s = (const float*)d_in[3];
    const float* b1r   = (const float*)d_in[4];
    const float* W1b_n = (const float*)d_in[5];
    const float* W1b_s = (const float*)d_in[6];
    const float* b1b   = (const float*)d_in[7];
    const float* W2r_n = (const float*)d_in[8];
    const float* W2r_s = (const float*)d_in[9];
    const float* b2r   = (const float*)d_in[10];
    const float* W2b_n = (const float*)d_in[11];
    const float* W2b_s = (const float*)d_in[12];
    const float* b2b   = (const float*)d_in[13];
    const int* e0r_src = (const int*)d_in[14];
    const int* e0r_dst = (const int*)d_in[15];
    const int* e0b_src = (const int*)d_in[16];
    const int* e0b_dst = (const int*)d_in[17];
    const int* e1r_src = (const int*)d_in[18];
    const int* e1r_dst = (const int*)d_in[19];
    const int* e1b_src = (const int*)d_in[20];
    const int* e1b_dst = (const int*)d_in[21];

    // ---- workspace layout ----
    constexpr size_t MPAD = 40064;  // cD0 padded up for BM=128 tail
    char* w = (char*)d_ws;
    size_t o = 0;
    auto take = [&](size_t bytes) -> void* {
        void* p = w + o; o += (bytes + 255) & ~(size_t)255; return p;
    };
    unsigned short* h1m   = (unsigned short*)take(MPAD * cDH * 2);
    unsigned short* h1u   = (unsigned short*)take(MPAD * cDH * 2);
    unsigned short* aggR  = (unsigned short*)take(MPAD * cDIN * 2);
    unsigned short* aggB  = (unsigned short*)take(MPAD * cDIN * 2);
    unsigned short* agg2R = (unsigned short*)take((size_t)cD1 * cDH * 2);
    unsigned short* agg2B = (unsigned short*)take((size_t)cD1 * cDH * 2);
    unsigned short* wt    = (unsigned short*)take((size_t)8 * 131072 * 2);
    unsigned short* xub   = (unsigned short*)take((size_t)cS0 * cDIN * 2);
    unsigned short* xmb   = (unsigned short*)take((size_t)cS0 * cDIN * 2);
    int* deg_all = (int*)take((size_t)2 * NTOT * 4);   // deg + cur contiguous (one memset)
    int* cur_all = deg_all + NTOT;
    int* off_all = (int*)take((size_t)NTOT * 4);
    int* btot    = (int*)take(512);
    int* csr_all = (int*)take((size_t)ETOT * 4);
    if (ws_size < o) return;  // insufficient workspace: fail visibly

    const int* off0 = off_all;
    const int* off1 = off_all + P0;
    const int* off2 = off_all + 2 * P0;
    const int* off3 = off_all + 2 * P0 + P1;
    const int* csr0 = csr_all;
    const int* csr1 = csr_all + cE0;
    const int* csr2 = csr_all + 2 * cE0;
    const int* csr3 = csr_all + 2 * cE0 + cE1;

    float* out_u2 = (float*)d_out;
    float* out_m2 = (float*)d_out + (size_t)cD1 * cDOUT;

    // 1) zero deg+cur
    hipMemsetAsync(deg_all, 0, (size_t)2 * NTOT * 4, stream);
    // 2) bf16 conversions
    k_cvt_all<<<(unsigned)((size_t)2 * cS0 * cDIN / 8 / 256), 256, 0, stream>>>(x_user, x_movie, xub, xmb);
    // 3) weight transposes
    WPtrs WP;
    WP.w[0] = W1r_s; WP.w[1] = W1r_n; WP.w[2] = W1b_s; WP.w[3] = W1b_n;
    WP.w[4] = W2r_s; WP.w[5] = W2r_n; WP.w[6] = W2b_s; WP.w[7] = W2b_n;
    k_wt_all<<<4096, 256, 0, stream>>>(WP, wt);
    // 4-8) CSR build (all 4 relations)
    k_deg_all<<<(ETOT + 255) / 256, 256, 0, stream>>>(e0r_dst, e0b_dst, e1r_dst, e1b_dst, deg_all);
    k_scanA<<<NBLK, 256, 0, stream>>>(deg_all, off_all, btot);
    k_scanB<<<1, 128, 0, stream>>>(btot);
    k_scanC<<<NBLK, 256, 0, stream>>>(off_all, btot);
    k_fill_all<<<(ETOT + 255) / 256, 256, 0, stream>>>(
        e0r_src, e0r_dst, e0b_src, e0b_dst, e1r_src, e1r_dst, e1b_src, e1b_dst,
        off_all, cur_all, csr_all);

    // 9) layer-1 aggregation: rel0 'rates' src=user, rel1 'rated_by' src=movie
    k_agg2<cDIN><<<2 * (cD0 / 4), 256, 0, stream>>>(
        xub, off0, csr0, aggR, xmb, off1, csr1, aggB, cD0);
    // 10) layer-1 dual GEMM: [h1m | h1u], BM=128, mtiles=313 (tail rows padded)
    k_gemm2<128, cDIN, cDH, true, true><<<2 * 313 * (cDH / 128), 256, 0, stream>>>(
        xmb, aggR, wt + 0 * 131072, wt + 1 * 131072, b1r, h1m,
        xub, aggB, wt + 2 * 131072, wt + 3 * 131072, b1b, h1u, 313);

    // 11) layer-2 aggregation: rel0 src=u1(h1u), rel1 src=m1(h1m)
    k_agg2<cDH><<<2 * (cD1 / 4), 256, 0, stream>>>(
        h1u, off2, csr2, agg2R, h1m, off3, csr3, agg2B, cD1);
    // 12) layer-2 dual GEMM: [m2 | u2], BM=64, mtiles=128
    k_gemm2<64, cDH, cDOUT, false, false><<<2 * 128 * (cDOUT / 128), 256, 0, stream>>>(
        h1m, agg2R, wt + 4 * 131072, wt + 5 * 131072, b2r, out_m2,
        h1u, agg2B, wt + 6 * 131072, wt + 7 * 131072, b2b, out_u2, 128);
}

// Round 4
// 476.441 us; speedup vs baseline: 2.9818x; 1.1846x over previous
//
#include <hip/hip_runtime.h>
#include <stdint.h>

#define DEV_INLINE __device__ __forceinline__

constexpr int cS0 = 200000, cD0 = 40000, cD1 = 8192;
constexpr int cE0 = 640000, cE1 = 131072;
constexpr int cDIN = 256, cDH = 512, cDOUT = 256;

// padded per-relation node-region sizes (multiples of 1024; D1 regions get +1024 so off[n] exists)
constexpr int P0 = 40960, P1 = 9216;
constexpr int NTOT = 2 * P0 + 2 * P1;   // 100352
constexpr int NBLK = NTOT / 1024;       // 98
constexpr int ETOT = 2 * cE0 + 2 * cE1; // 1542144

typedef __attribute__((ext_vector_type(8))) short bf16x8_t;
typedef __attribute__((ext_vector_type(4))) float f32x4_t;

DEV_INLINE float bf2f(unsigned short u) {
    union { unsigned int i; float f; } x; x.i = ((unsigned int)u) << 16; return x.f;
}
DEV_INLINE unsigned short f2bf(float f) {
    union { float f; unsigned int i; } x; x.f = f;
    unsigned int r = x.i + 0x7FFF + ((x.i >> 16) & 1);
    return (unsigned short)(r >> 16);
}

DEV_INLINE void gload_lds16(const void* g, void* l) {
    __builtin_amdgcn_global_load_lds(
        (__attribute__((address_space(1))) void*)(uintptr_t)g,
        (__attribute__((address_space(3))) void*)(uintptr_t)l,
        16, 0, 0);
}

// ---------------- fp32 -> bf16 conversion (both x tables, one kernel) ----------------

__global__ __launch_bounds__(256) void k_cvt_all(const float* __restrict__ a, const float* __restrict__ b,
                                                 unsigned short* __restrict__ oa, unsigned short* __restrict__ ob) {
    const long n8 = (long)cS0 * cDIN / 8;
    long i = (long)blockIdx.x * 256 + threadIdx.x;
    const float* in; unsigned short* out;
    if (i >= n8) { in = b; out = ob; i -= n8; } else { in = a; out = oa; }
    const float4* p = (const float4*)(in + i * 8);
    float4 u = p[0], v = p[1];
    union { unsigned short us[8]; uint4 q; } pk;
    pk.us[0] = f2bf(u.x); pk.us[1] = f2bf(u.y); pk.us[2] = f2bf(u.z); pk.us[3] = f2bf(u.w);
    pk.us[4] = f2bf(v.x); pk.us[5] = f2bf(v.y); pk.us[6] = f2bf(v.z); pk.us[7] = f2bf(v.w);
    *(uint4*)(out + i * 8) = pk.q;
}

// ---------------- all 8 weight transposes: W[K][N] fp32 -> Wt[N][K] bf16 ----------------

struct WPtrs { const float* w[8]; };

__global__ __launch_bounds__(256) void k_wt_all(WPtrs W, unsigned short* __restrict__ wt) {
    int idx = blockIdx.x * 256 + threadIdx.x;      // 8 * 131072 total
    int slot = idx >> 17, e = idx & 131071;
    int K = slot < 4 ? cDIN : cDH;
    int N = slot < 4 ? cDH : cDOUT;
    int n = e / K, k = e % K;
    wt[idx] = f2bf(W.w[slot][(size_t)k * N + n]);
}

// ---------------- CSR build over all 4 relations ----------------

__global__ __launch_bounds__(256) void k_deg_all(const int* __restrict__ d0, const int* __restrict__ d1,
                                                 const int* __restrict__ d2, const int* __restrict__ d3,
                                                 int* __restrict__ deg) {
    int i = blockIdx.x * 256 + threadIdx.x;
    if (i >= ETOT) return;
    const int* dp; int base, noff;
    if (i < cE0)               { dp = d0; base = 0;           noff = 0; }
    else if (i < 2 * cE0)      { dp = d1; base = cE0;         noff = P0; }
    else if (i < 2 * cE0 + cE1){ dp = d2; base = 2 * cE0;     noff = 2 * P0; }
    else                       { dp = d3; base = 2 * cE0 + cE1; noff = 2 * P0 + P1; }
    atomicAdd(&deg[noff + dp[i - base]], 1);
}

// per-1024-element block exclusive scan + block totals
__global__ __launch_bounds__(256) void k_scanA(const int* __restrict__ deg, int* __restrict__ off,
                                               int* __restrict__ btot) {
    __shared__ int buf[256];
    int t = threadIdx.x;
    long base = (long)blockIdx.x * 1024;
    int4 v = *(const int4*)(deg + base + t * 4);
    int s1 = v.x + v.y, s2 = s1 + v.z, ts = s2 + v.w;
    buf[t] = ts; __syncthreads();
    for (int o = 1; o < 256; o <<= 1) {
        int u = (t >= o) ? buf[t - o] : 0;
        __syncthreads(); buf[t] += u; __syncthreads();
    }
    int ex = buf[t] - ts;
    int4 w; w.x = ex; w.y = ex + v.x; w.z = ex + s1; w.w = ex + s2;
    *(int4*)(off + base + t * 4) = w;
    if (t == 255) btot[blockIdx.x] = buf[255];
}

// segmented exclusive scan of the 98 block totals (segments = 4 node regions)
__global__ void k_scanB(int* __restrict__ bt) {
    __shared__ int buf[128];
    __shared__ int seg[128];
    int t = threadIdx.x;
    int s = (t >= 89) ? 3 : (t >= 80) ? 2 : (t >= 40) ? 1 : 0;
    int v = (t < NBLK) ? bt[t] : 0;
    buf[t] = v; seg[t] = s; __syncthreads();
    for (int o = 1; o < 128; o <<= 1) {
        int u = 0;
        if (t >= o && seg[t - o] == s) u = buf[t - o];
        __syncthreads(); buf[t] += u; __syncthreads();
    }
    if (t < NBLK) bt[t] = buf[t] - v;   // exclusive within segment
}

__global__ __launch_bounds__(256) void k_scanC(int* __restrict__ off, const int* __restrict__ bt) {
    int t = threadIdx.x;
    long base = (long)blockIdx.x * 1024;
    int bo = bt[blockIdx.x];
    int4 v = *(int4*)(off + base + t * 4);
    v.x += bo; v.y += bo; v.z += bo; v.w += bo;
    *(int4*)(off + base + t * 4) = v;
}

__global__ __launch_bounds__(256) void k_fill_all(
    const int* __restrict__ s0, const int* __restrict__ d0, const int* __restrict__ s1, const int* __restrict__ d1,
    const int* __restrict__ s2, const int* __restrict__ d2, const int* __restrict__ s3, const int* __restrict__ d3,
    const int* __restrict__ off, int* __restrict__ cur, int* __restrict__ csr) {
    int i = blockIdx.x * 256 + threadIdx.x;
    if (i >= ETOT) return;
    const int* sp; const int* dp; int base, noff, cbase;
    if (i < cE0)               { sp = s0; dp = d0; base = 0;            noff = 0;           cbase = 0; }
    else if (i < 2 * cE0)      { sp = s1; dp = d1; base = cE0;          noff = P0;          cbase = cE0; }
    else if (i < 2 * cE0 + cE1){ sp = s2; dp = d2; base = 2 * cE0;      noff = 2 * P0;      cbase = 2 * cE0; }
    else                       { sp = s3; dp = d3; base = 2 * cE0 + cE1; noff = 2 * P0 + P1; cbase = 2 * cE0 + cE1; }
    int li = i - base;
    int d = dp[li];
    int p = atomicAdd(&cur[noff + d], 1);
    csr[cbase + off[noff + d] + p] = sp[li];
}

// ---------------- merged mean aggregation (2 relations per launch), bf16 in/out ----------------
// High-MLP version: 16B/lane row coverage.
//   K=256: half-wave (32 lanes) per edge slot, 2 edge slots/wave, x4 unroll -> 8 loads in flight.
//   K=512: full wave per edge, x4 unroll -> 4 loads in flight.

template <int K>
__global__ __launch_bounds__(256) void k_agg2(
    const unsigned short* __restrict__ x0, const int* __restrict__ off0, const int* __restrict__ csr0,
    unsigned short* __restrict__ o0,
    const unsigned short* __restrict__ x1, const int* __restrict__ off1, const int* __restrict__ csr1,
    unsigned short* __restrict__ o1, int ndst) {
    constexpr bool HALF = (K == 256);
    constexpr int ESTEP = HALF ? 2 : 1;     // edges per unroll slot
    int nb = ndst / 4;
    int b = blockIdx.x;
    const unsigned short* xs; const int* off; const int* csr; unsigned short* out;
    if (b >= nb) { xs = x1; off = off1; csr = csr1; out = o1; b -= nb; }
    else         { xs = x0; off = off0; csr = csr0; out = o0; }
    int lane = threadIdx.x & 63;
    int d = b * 4 + (threadIdx.x >> 6);
    int elane = HALF ? (lane & 31) : lane;  // 16B-granule index within row
    int eslot = HALF ? (lane >> 5) : 0;

    float acc[8];
#pragma unroll
    for (int i = 0; i < 8; i++) acc[i] = 0.f;
    int p0 = off[d], p1 = off[d + 1];

    for (int p = p0; p < p1; p += 4 * ESTEP) {
        int idx[4];
#pragma unroll
        for (int u = 0; u < 4; ++u) {
            int q = p + u * ESTEP + eslot;
            idx[u] = (q < p1) ? csr[q] : -1;
        }
#pragma unroll
        for (int u = 0; u < 4; ++u) {
            if (idx[u] >= 0) {
                uint4 v = *(const uint4*)(xs + (size_t)idx[u] * K + elane * 8);
                const unsigned short* us = (const unsigned short*)&v;
#pragma unroll
                for (int i = 0; i < 8; ++i) acc[i] += bf2f(us[i]);
            }
        }
    }
    if constexpr (HALF) {
#pragma unroll
        for (int i = 0; i < 8; ++i) acc[i] += __shfl_xor(acc[i], 32);
    }
    int dg = p1 - p0;
    float sc = 1.0f / (float)(dg > 1 ? dg : 1);
    union { unsigned short us[8]; uint4 v4; } pk;
#pragma unroll
    for (int i = 0; i < 8; i++) pk.us[i] = f2bf(acc[i] * sc);
    if (!HALF || lane < 32)
        *(uint4*)(out + (size_t)d * K + (size_t)elane * 8) = pk.v4;
}

// ---------------- fused SAGE GEMM (MFMA bf16), 2 relations per launch ----------------
// out = act( Aself@Wself + Aagg@Wneigh + bias ); K concat as 2 segments of KSEG.
// BMxBN tile (BN=128), BK=64; 4 waves 2x2; wave tile (BM/2)x64.
// LDS rows of 64 bf16 (128B = 8 x 16B chunks); chunk-XOR swizzle phys = logical ^ (row&7),
// applied on the *global source* address (LDS dest stays linear for global_load_lds).
// Block index XCD-swizzled (grid must be a multiple of 8).

template <int BM, int KSEG, int N, bool OUT_BF16, bool RELU>
__global__ __launch_bounds__(256) void k_gemm2(
    const unsigned short* __restrict__ aself0, const unsigned short* __restrict__ aagg0,
    const unsigned short* __restrict__ bts0, const unsigned short* __restrict__ btn0,
    const float* __restrict__ bias0, void* __restrict__ out0,
    const unsigned short* __restrict__ aself1, const unsigned short* __restrict__ aagg1,
    const unsigned short* __restrict__ bts1, const unsigned short* __restrict__ btn1,
    const float* __restrict__ bias1, void* __restrict__ out1,
    int mtiles) {
    constexpr int BN = 128, BK = 64;
    constexpr int H = KSEG / BK, NSTEP = 2 * H;
    constexpr int WROWS = BM / 2, FM = WROWS / 16;   // frags per wave (row dim)
    constexpr int AIT = BM / 32;                     // A staging iterations
    __shared__ __align__(16) unsigned short As[2][BM * BK];
    __shared__ __align__(16) unsigned short Bs[2][BN * BK];

    const int tiles_n = N / BN;
    const int gpr = mtiles * tiles_n;
    // XCD-aware swizzle (gridDim.x % 8 == 0): contiguous logical chunk per XCD
    int b = blockIdx.x;
    {
        int cpx = gridDim.x >> 3;
        b = (b & 7) * cpx + (b >> 3);
    }
    const unsigned short *aself, *aagg, *bts, *btn; const float* bias; void* out;
    if (b >= gpr) { b -= gpr; aself = aself1; aagg = aagg1; bts = bts1; btn = btn1; bias = bias1; out = out1; }
    else          {           aself = aself0; aagg = aagg0; bts = bts0; btn = btn0; bias = bias0; out = out0; }
    const int m0 = (b / tiles_n) * BM;
    const int n0 = (b % tiles_n) * BN;
    const int t = threadIdx.x, lane = t & 63, wave = t >> 6;
    const int wr = wave >> 1, wc = wave & 1;
    const int l15 = lane & 15, l4 = lane >> 4;

    f32x4_t acc[FM][4];
    const f32x4_t zero = {0.f, 0.f, 0.f, 0.f};
#pragma unroll
    for (int i = 0; i < FM; i++)
#pragma unroll
        for (int j = 0; j < 4; j++) acc[i][j] = zero;

    auto stage = [&](int buf, int s) {
        const int seg = (s >= H) ? 1 : 0;
        const int k0 = (s - seg * H) * BK;
        const unsigned short* A = seg ? aagg : aself;
        const unsigned short* B = seg ? btn : bts;
#pragma unroll
        for (int it = 0; it < AIT; ++it) {          // A: BM rows x 8 chunks
            int c = it * 256 + t;
            int row = c >> 3;
            int lch = (c & 7) ^ (row & 7);
            gload_lds16(A + (size_t)(m0 + row) * KSEG + k0 + lch * 8,
                        (char*)&As[buf][0] + (it * 256 + wave * 64) * 16);
        }
#pragma unroll
        for (int it = 0; it < 4; ++it) {            // B: 128 rows x 8 chunks
            int c = it * 256 + t;
            int row = c >> 3;
            int lch = (c & 7) ^ (row & 7);
            gload_lds16(B + (size_t)(n0 + row) * KSEG + k0 + lch * 8,
                        (char*)&Bs[buf][0] + (it * 256 + wave * 64) * 16);
        }
    };

    int cur = 0;
    stage(0, 0);
    for (int s = 0; s < NSTEP; ++s) {
        __syncthreads();                  // drains vmcnt -> buf[cur] staged; prior reads done
        if (s + 1 < NSTEP) stage(cur ^ 1, s + 1);
        const char* Ab = (const char*)&As[cur][0];
        const char* Bb = (const char*)&Bs[cur][0];
        bf16x8_t a[FM][2], bb[4][2];
#pragma unroll
        for (int fm = 0; fm < FM; ++fm) {
            int row = wr * WROWS + fm * 16 + l15;
#pragma unroll
            for (int ks = 0; ks < 2; ++ks) {
                int pc = (ks * 4 + l4) ^ (row & 7);
                a[fm][ks] = *(const bf16x8_t*)(Ab + row * 128 + pc * 16);
            }
        }
#pragma unroll
        for (int fn = 0; fn < 4; ++fn) {
            int row = wc * 64 + fn * 16 + l15;
#pragma unroll
            for (int ks = 0; ks < 2; ++ks) {
                int pc = (ks * 4 + l4) ^ (row & 7);
                bb[fn][ks] = *(const bf16x8_t*)(Bb + row * 128 + pc * 16);
            }
        }
#pragma unroll
        for (int ks = 0; ks < 2; ++ks)
#pragma unroll
            for (int fm = 0; fm < FM; ++fm)
#pragma unroll
                for (int fn = 0; fn < 4; ++fn)
                    acc[fm][fn] = __builtin_amdgcn_mfma_f32_16x16x32_bf16(
                        a[fm][ks], bb[fn][ks], acc[fm][fn], 0, 0, 0);
        cur ^= 1;
    }

#pragma unroll
    for (int fm = 0; fm < FM; ++fm) {
#pragma unroll
        for (int fn = 0; fn < 4; ++fn) {
            int col = n0 + wc * 64 + fn * 16 + l15;
            float bv = bias[col];
            f32x4_t v = acc[fm][fn];
#pragma unroll
            for (int r = 0; r < 4; ++r) {
                int rowg = m0 + wr * WROWS + fm * 16 + l4 * 4 + r;
                float o = v[r] + bv;
                if (RELU) o = fmaxf(o, 0.f);
                if constexpr (OUT_BF16)
                    ((unsigned short*)out)[(size_t)rowg * N + col] = f2bf(o);
                else
                    ((float*)out)[(size_t)rowg * N + col] = o;
            }
        }
    }
}

// ---------------- launch ----------------

extern "C" void kernel_launch(void* const* d_in, const int* in_sizes, int n_in,
                              void* d_out, int out_size, void* d_ws, size_t ws_size,
                              hipStream_t stream) {
    const float* x_user  = (const float*)d_in[0];
    const float* x_movie = (const float*)d_in[1];
    const float* W1r_n = (const float*)d_in[2];
    const float* W1r_s = (const float*)d_in[3];
    const float* b1r   = (const float*)d_in[4];
    const float* W1b_n = (const float*)d_in[5];
    const float* W1b_s = (const float*)d_in[6];
    const float* b1b   = (const float*)d_in[7];
    const float* W2r_n = (const float*)d_in[8];
    const float* W2r_s = (const float*)d_in[9];
    const float* b2r   = (const float*)d_in[10];
    const float* W2b_n = (const float*)d_in[11];
    const float* W2b_s = (const float*)d_in[12];
    const float* b2b   = (const float*)d_in[13];
    const int* e0r_src = (const int*)d_in[14];
    const int* e0r_dst = (const int*)d_in[15];
    const int* e0b_src = (const int*)d_in[16];
    const int* e0b_dst = (const int*)d_in[17];
    const int* e1r_src = (const int*)d_in[18];
    const int* e1r_dst = (const int*)d_in[19];
    const int* e1b_src = (const int*)d_in[20];
    const int* e1b_dst = (const int*)d_in[21];

    // ---- workspace layout ----
    constexpr size_t MPAD = 40064;  // cD0 padded up for BM=128 tail
    char* w = (char*)d_ws;
    size_t o = 0;
    auto take = [&](size_t bytes) -> void* {
        void* p = w + o; o += (bytes + 255) & ~(size_t)255; return p;
    };
    unsigned short* h1m   = (unsigned short*)take(MPAD * cDH * 2);
    unsigned short* h1u   = (unsigned short*)take(MPAD * cDH * 2);
    unsigned short* aggR  = (unsigned short*)take(MPAD * cDIN * 2);
    unsigned short* aggB  = (unsigned short*)take(MPAD * cDIN * 2);
    unsigned short* agg2R = (unsigned short*)take((size_t)cD1 * cDH * 2);
    unsigned short* agg2B = (unsigned short*)take((size_t)cD1 * cDH * 2);
    unsigned short* wt    = (unsigned short*)take((size_t)8 * 131072 * 2);
    unsigned short* xub   = (unsigned short*)take((size_t)cS0 * cDIN * 2);
    unsigned short* xmb   = (unsigned short*)take((size_t)cS0 * cDIN * 2);
    int* deg_all = (int*)take((size_t)2 * NTOT * 4);   // deg + cur contiguous (one memset)
    int* cur_all = deg_all + NTOT;
    int* off_all = (int*)take((size_t)NTOT * 4);
    int* btot    = (int*)take(512);
    int* csr_all = (int*)take((size_t)ETOT * 4);
    if (ws_size < o) return;  // insufficient workspace: fail visibly

    const int* off0 = off_all;
    const int* off1 = off_all + P0;
    const int* off2 = off_all + 2 * P0;
    const int* off3 = off_all + 2 * P0 + P1;
    const int* csr0 = csr_all;
    const int* csr1 = csr_all + cE0;
    const int* csr2 = csr_all + 2 * cE0;
    const int* csr3 = csr_all + 2 * cE0 + cE1;

    float* out_u2 = (float*)d_out;
    float* out_m2 = (float*)d_out + (size_t)cD1 * cDOUT;

    // 1) zero deg+cur
    hipMemsetAsync(deg_all, 0, (size_t)2 * NTOT * 4, stream);
    // 2) bf16 conversions
    k_cvt_all<<<(unsigned)((size_t)2 * cS0 * cDIN / 8 / 256), 256, 0, stream>>>(x_user, x_movie, xub, xmb);
    // 3) weight transposes
    WPtrs WP;
    WP.w[0] = W1r_s; WP.w[1] = W1r_n; WP.w[2] = W1b_s; WP.w[3] = W1b_n;
    WP.w[4] = W2r_s; WP.w[5] = W2r_n; WP.w[6] = W2b_s; WP.w[7] = W2b_n;
    k_wt_all<<<4096, 256, 0, stream>>>(WP, wt);
    // 4-8) CSR build (all 4 relations)
    k_deg_all<<<(ETOT + 255) / 256, 256, 0, stream>>>(e0r_dst, e0b_dst, e1r_dst, e1b_dst, deg_all);
    k_scanA<<<NBLK, 256, 0, stream>>>(deg_all, off_all, btot);
    k_scanB<<<1, 128, 0, stream>>>(btot);
    k_scanC<<<NBLK, 256, 0, stream>>>(off_all, btot);
    k_fill_all<<<(ETOT + 255) / 256, 256, 0, stream>>>(
        e0r_src, e0r_dst, e0b_src, e0b_dst, e1r_src, e1r_dst, e1b_src, e1b_dst,
        off_all, cur_all, csr_all);

    // 9) layer-1 aggregation: rel0 'rates' src=user, rel1 'rated_by' src=movie
    k_agg2<cDIN><<<2 * (cD0 / 4), 256, 0, stream>>>(
        xub, off0, csr0, aggR, xmb, off1, csr1, aggB, cD0);
    // 10) layer-1 dual GEMM: [h1m | h1u], BM=128, mtiles=313 (tail rows padded)
    k_gemm2<128, cDIN, cDH, true, true><<<2 * 313 * (cDH / 128), 256, 0, stream>>>(
        xmb, aggR, wt + 0 * 131072, wt + 1 * 131072, b1r, h1m,
        xub, aggB, wt + 2 * 131072, wt + 3 * 131072, b1b, h1u, 313);

    // 11) layer-2 aggregation: rel0 src=u1(h1u), rel1 src=m1(h1m)
    k_agg2<cDH><<<2 * (cD1 / 4), 256, 0, stream>>>(
        h1u, off2, csr2, agg2R, h1m, off3, csr3, agg2B, cD1);
    // 12) layer-2 dual GEMM: [m2 | u2], BM=64, mtiles=128
    k_gemm2<64, cDH, cDOUT, false, false><<<2 * 128 * (cDOUT / 128), 256, 0, stream>>>(
        h1m, agg2R, wt + 4 * 131072, wt + 5 * 131072, b2r, out_m2,
        h1u, agg2B, wt + 6 * 131072, wt + 7 * 131072, b2b, out_u2, 128);
}

// Round 6
// 462.505 us; speedup vs baseline: 3.0716x; 1.0301x over previous
//
#include <hip/hip_runtime.h>
#include <stdint.h>

#define DEV_INLINE __device__ __forceinline__

constexpr int cS0 = 200000, cD0 = 40000, cD1 = 8192;
constexpr int cE0 = 640000, cE1 = 131072;
constexpr int cDIN = 256, cDH = 512, cDOUT = 256;

// padded per-relation node-region sizes (multiples of 1024; D1 regions get +1024 so off[n] exists)
constexpr int P0 = 40960, P1 = 9216;
constexpr int NTOT = 2 * P0 + 2 * P1;   // 100352
constexpr int NBLK = NTOT / 1024;       // 98
constexpr int ETOT = 2 * cE0 + 2 * cE1; // 1542144

// fused front kernel block partition
constexpr int NCVT_BLK = (2 * cS0 * cDIN / 4) / 256;  // 100000 (one float4 per thread)
constexpr int NWT_BLK  = 4096;                        // 8 * 131072 / 256
constexpr int NDEG_BLK = (ETOT + 255) / 256;          // 6024

typedef __attribute__((ext_vector_type(8))) short bf16x8_t;
typedef __attribute__((ext_vector_type(4))) float f32x4_t;

DEV_INLINE float bf2f(unsigned short u) {
    union { unsigned int i; float f; } x; x.i = ((unsigned int)u) << 16; return x.f;
}
DEV_INLINE unsigned short f2bf(float f) {
    union { float f; unsigned int i; } x; x.f = f;
    unsigned int r = x.i + 0x7FFF + ((x.i >> 16) & 1);
    return (unsigned short)(r >> 16);
}

DEV_INLINE void gload_lds16(const void* g, void* l) {
    __builtin_amdgcn_global_load_lds(
        (__attribute__((address_space(1))) void*)(uintptr_t)g,
        (__attribute__((address_space(3))) void*)(uintptr_t)l,
        16, 0, 0);
}

struct WPtrs { const float* w[8]; };

// ---------------- fused front: x->bf16 convert | weight transpose | degree count ----------------

__global__ __launch_bounds__(256) void k_front(
    const float* __restrict__ xu, const float* __restrict__ xm,
    unsigned short* __restrict__ ou, unsigned short* __restrict__ om,
    WPtrs W, unsigned short* __restrict__ wt,
    const int* __restrict__ d0, const int* __restrict__ d1,
    const int* __restrict__ d2, const int* __restrict__ d3,
    int* __restrict__ deg) {
    int b = blockIdx.x;
    if (b < NCVT_BLK) {
        // dense: lane-consecutive float4 -> per-instruction 1KB/wave; NT read (no L3 pollution)
        long i = (long)b * 256 + threadIdx.x;     // float4 index
        const long nq = (long)cS0 * cDIN / 4;     // 12.8M float4 per table
        const float* in; unsigned short* out;
        if (i >= nq) { in = xm; out = om; i -= nq; }
        else         { in = xu; out = ou; }
        f32x4_t v = __builtin_nontemporal_load((const f32x4_t*)in + i);
        union { unsigned short us[4]; uint2 q; } pk;
        pk.us[0] = f2bf(v.x); pk.us[1] = f2bf(v.y); pk.us[2] = f2bf(v.z); pk.us[3] = f2bf(v.w);
        *(uint2*)(out + i * 4) = pk.q;            // cached: agg gathers these next
        return;
    }
    b -= NCVT_BLK;
    if (b < NWT_BLK) {                            // W [K][N] fp32 -> Wt [N][K] bf16
        int idx = b * 256 + threadIdx.x;
        int slot = idx >> 17, e = idx & 131071;
        int K = slot < 4 ? cDIN : cDH;
        int N = slot < 4 ? cDH : cDOUT;
        int n = e / K, k = e % K;
        wt[idx] = f2bf(W.w[slot][(size_t)k * N + n]);
        return;
    }
    b -= NWT_BLK;
    int i = b * 256 + threadIdx.x;
    if (i >= ETOT) return;
    const int* dp; int base, noff;
    if (i < cE0)                { dp = d0; base = 0;             noff = 0; }
    else if (i < 2 * cE0)       { dp = d1; base = cE0;           noff = P0; }
    else if (i < 2 * cE0 + cE1) { dp = d2; base = 2 * cE0;       noff = 2 * P0; }
    else                        { dp = d3; base = 2 * cE0 + cE1; noff = 2 * P0 + P1; }
    atomicAdd(&deg[noff + dp[i - base]], 1);
}

// ---------------- CSR scan + fill ----------------

// per-1024-element block exclusive scan + block totals
__global__ __launch_bounds__(256) void k_scanA(const int* __restrict__ deg, int* __restrict__ off,
                                               int* __restrict__ btot) {
    __shared__ int buf[256];
    int t = threadIdx.x;
    long base = (long)blockIdx.x * 1024;
    int4 v = *(const int4*)(deg + base + t * 4);
    int s1 = v.x + v.y, s2 = s1 + v.z, ts = s2 + v.w;
    buf[t] = ts; __syncthreads();
    for (int o = 1; o < 256; o <<= 1) {
        int u = (t >= o) ? buf[t - o] : 0;
        __syncthreads(); buf[t] += u; __syncthreads();
    }
    int ex = buf[t] - ts;
    int4 w; w.x = ex; w.y = ex + v.x; w.z = ex + s1; w.w = ex + s2;
    *(int4*)(off + base + t * 4) = w;
    if (t == 255) btot[blockIdx.x] = buf[255];
}

// segmented exclusive scan of the 98 block totals (segments = 4 node regions)
__global__ void k_scanB(int* __restrict__ bt) {
    __shared__ int buf[128];
    __shared__ int seg[128];
    int t = threadIdx.x;
    int s = (t >= 89) ? 3 : (t >= 80) ? 2 : (t >= 40) ? 1 : 0;
    int v = (t < NBLK) ? bt[t] : 0;
    buf[t] = v; seg[t] = s; __syncthreads();
    for (int o = 1; o < 128; o <<= 1) {
        int u = 0;
        if (t >= o && seg[t - o] == s) u = buf[t - o];
        __syncthreads(); buf[t] += u; __syncthreads();
    }
    if (t < NBLK) bt[t] = buf[t] - v;   // exclusive within segment
}

__global__ __launch_bounds__(256) void k_scanC(int* __restrict__ off, const int* __restrict__ bt) {
    int t = threadIdx.x;
    long base = (long)blockIdx.x * 1024;
    int bo = bt[blockIdx.x];
    int4 v = *(int4*)(off + base + t * 4);
    v.x += bo; v.y += bo; v.z += bo; v.w += bo;
    *(int4*)(off + base + t * 4) = v;
}

__global__ __launch_bounds__(256) void k_fill_all(
    const int* __restrict__ s0, const int* __restrict__ d0, const int* __restrict__ s1, const int* __restrict__ d1,
    const int* __restrict__ s2, const int* __restrict__ d2, const int* __restrict__ s3, const int* __restrict__ d3,
    const int* __restrict__ off, int* __restrict__ cur, int* __restrict__ csr) {
    int i = blockIdx.x * 256 + threadIdx.x;
    if (i >= ETOT) return;
    const int* sp; const int* dp; int base, noff, cbase;
    if (i < cE0)                { sp = s0; dp = d0; base = 0;             noff = 0;           cbase = 0; }
    else if (i < 2 * cE0)       { sp = s1; dp = d1; base = cE0;           noff = P0;          cbase = cE0; }
    else if (i < 2 * cE0 + cE1) { sp = s2; dp = d2; base = 2 * cE0;       noff = 2 * P0;      cbase = 2 * cE0; }
    else                        { sp = s3; dp = d3; base = 2 * cE0 + cE1; noff = 2 * P0 + P1; cbase = 2 * cE0 + cE1; }
    int li = i - base;
    int d = dp[li];
    int p = atomicAdd(&cur[noff + d], 1);
    csr[cbase + off[noff + d] + p] = sp[li];
}

// ---------------- merged mean aggregation (2 relations per launch), bf16 in/out ----------------
// High-MLP: 16B/lane row coverage, 8-deep unroll.
//   K=256: half-wave (32 lanes) per edge slot, 2 edge slots/wave, x8 unroll -> 16 loads in flight.
//   K=512: full wave per edge, x8 unroll -> 8 loads in flight.

template <int K>
__global__ __launch_bounds__(256) void k_agg2(
    const unsigned short* __restrict__ x0, const int* __restrict__ off0, const int* __restrict__ csr0,
    unsigned short* __restrict__ o0,
    const unsigned short* __restrict__ x1, const int* __restrict__ off1, const int* __restrict__ csr1,
    unsigned short* __restrict__ o1, int ndst) {
    constexpr bool HALF = (K == 256);
    constexpr int ESTEP = HALF ? 2 : 1;     // edges per unroll slot
    constexpr int U = 8;
    int nb = ndst / 4;
    int b = blockIdx.x;
    const unsigned short* xs; const int* off; const int* csr; unsigned short* out;
    if (b >= nb) { xs = x1; off = off1; csr = csr1; out = o1; b -= nb; }
    else         { xs = x0; off = off0; csr = csr0; out = o0; }
    int lane = threadIdx.x & 63;
    int d = b * 4 + (threadIdx.x >> 6);
    int elane = HALF ? (lane & 31) : lane;  // 16B-granule index within row
    int eslot = HALF ? (lane >> 5) : 0;

    float acc[8];
#pragma unroll
    for (int i = 0; i < 8; i++) acc[i] = 0.f;
    int p0 = off[d], p1 = off[d + 1];

    for (int p = p0; p < p1; p += U * ESTEP) {
        int idx[U];
#pragma unroll
        for (int u = 0; u < U; ++u) {
            int q = p + u * ESTEP + eslot;
            idx[u] = (q < p1) ? csr[q] : -1;
        }
#pragma unroll
        for (int u = 0; u < U; ++u) {
            if (idx[u] >= 0) {
                uint4 v = *(const uint4*)(xs + (size_t)idx[u] * K + elane * 8);
                const unsigned short* us = (const unsigned short*)&v;
#pragma unroll
                for (int i = 0; i < 8; ++i) acc[i] += bf2f(us[i]);
            }
        }
    }
    if constexpr (HALF) {
#pragma unroll
        for (int i = 0; i < 8; ++i) acc[i] += __shfl_xor(acc[i], 32);
    }
    int dg = p1 - p0;
    float sc = 1.0f / (float)(dg > 1 ? dg : 1);
    union { unsigned short us[8]; uint4 v4; } pk;
#pragma unroll
    for (int i = 0; i < 8; i++) pk.us[i] = f2bf(acc[i] * sc);
    if (!HALF || lane < 32)
        *(uint4*)(out + (size_t)d * K + (size_t)elane * 8) = pk.v4;
}

// ---------------- fused SAGE GEMM (MFMA bf16), 2 relations per launch ----------------
// out = act( Aself@Wself + Aagg@Wneigh + bias ); K concat as 2 segments of KSEG.
// BMxBN tile (BN=128), BK=64; 4 waves 2x2; wave tile (BM/2)x64.
// LDS rows of 64 bf16 (128B = 8 x 16B chunks); chunk-XOR swizzle phys = logical ^ (row&7),
// applied on the *global source* address (LDS dest stays linear for global_load_lds).
// Block index XCD-swizzled (grid must be a multiple of 8).

template <int BM, int KSEG, int N, bool OUT_BF16, bool RELU>
__global__ __launch_bounds__(256) void k_gemm2(
    const unsigned short* __restrict__ aself0, const unsigned short* __restrict__ aagg0,
    const unsigned short* __restrict__ bts0, const unsigned short* __restrict__ btn0,
    const float* __restrict__ bias0, void* __restrict__ out0,
    const unsigned short* __restrict__ aself1, const unsigned short* __restrict__ aagg1,
    const unsigned short* __restrict__ bts1, const unsigned short* __restrict__ btn1,
    const float* __restrict__ bias1, void* __restrict__ out1,
    int mtiles) {
    constexpr int BN = 128, BK = 64;
    constexpr int H = KSEG / BK, NSTEP = 2 * H;
    constexpr int WROWS = BM / 2, FM = WROWS / 16;   // frags per wave (row dim)
    constexpr int AIT = BM / 32;                     // A staging iterations
    __shared__ __align__(16) unsigned short As[2][BM * BK];
    __shared__ __align__(16) unsigned short Bs[2][BN * BK];

    const int tiles_n = N / BN;
    const int gpr = mtiles * tiles_n;
    // XCD-aware swizzle (gridDim.x % 8 == 0): contiguous logical chunk per XCD
    int b = blockIdx.x;
    {
        int cpx = gridDim.x >> 3;
        b = (b & 7) * cpx + (b >> 3);
    }
    const unsigned short *aself, *aagg, *bts, *btn; const float* bias; void* out;
    if (b >= gpr) { b -= gpr; aself = aself1; aagg = aagg1; bts = bts1; btn = btn1; bias = bias1; out = out1; }
    else          {           aself = aself0; aagg = aagg0; bts = bts0; btn = btn0; bias = bias0; out = out0; }
    const int m0 = (b / tiles_n) * BM;
    const int n0 = (b % tiles_n) * BN;
    const int t = threadIdx.x, lane = t & 63, wave = t >> 6;
    const int wr = wave >> 1, wc = wave & 1;
    const int l15 = lane & 15, l4 = lane >> 4;

    f32x4_t acc[FM][4];
    const f32x4_t zero = {0.f, 0.f, 0.f, 0.f};
#pragma unroll
    for (int i = 0; i < FM; i++)
#pragma unroll
        for (int j = 0; j < 4; j++) acc[i][j] = zero;

    auto stage = [&](int buf, int s) {
        const int seg = (s >= H) ? 1 : 0;
        const int k0 = (s - seg * H) * BK;
        const unsigned short* A = seg ? aagg : aself;
        const unsigned short* B = seg ? btn : bts;
#pragma unroll
        for (int it = 0; it < AIT; ++it) {          // A: BM rows x 8 chunks
            int c = it * 256 + t;
            int row = c >> 3;
            int lch = (c & 7) ^ (row & 7);
            gload_lds16(A + (size_t)(m0 + row) * KSEG + k0 + lch * 8,
                        (char*)&As[buf][0] + (it * 256 + wave * 64) * 16);
        }
#pragma unroll
        for (int it = 0; it < 4; ++it) {            // B: 128 rows x 8 chunks
            int c = it * 256 + t;
            int row = c >> 3;
            int lch = (c & 7) ^ (row & 7);
            gload_lds16(B + (size_t)(n0 + row) * KSEG + k0 + lch * 8,
                        (char*)&Bs[buf][0] + (it * 256 + wave * 64) * 16);
        }
    };

    int cur = 0;
    stage(0, 0);
    for (int s = 0; s < NSTEP; ++s) {
        __syncthreads();                  // drains vmcnt -> buf[cur] staged; prior reads done
        if (s + 1 < NSTEP) stage(cur ^ 1, s + 1);
        const char* Ab = (const char*)&As[cur][0];
        const char* Bb = (const char*)&Bs[cur][0];
        bf16x8_t a[FM][2], bb[4][2];
#pragma unroll
        for (int fm = 0; fm < FM; ++fm) {
            int row = wr * WROWS + fm * 16 + l15;
#pragma unroll
            for (int ks = 0; ks < 2; ++ks) {
                int pc = (ks * 4 + l4) ^ (row & 7);
                a[fm][ks] = *(const bf16x8_t*)(Ab + row * 128 + pc * 16);
            }
        }
#pragma unroll
        for (int fn = 0; fn < 4; ++fn) {
            int row = wc * 64 + fn * 16 + l15;
#pragma unroll
            for (int ks = 0; ks < 2; ++ks) {
                int pc = (ks * 4 + l4) ^ (row & 7);
                bb[fn][ks] = *(const bf16x8_t*)(Bb + row * 128 + pc * 16);
            }
        }
#pragma unroll
        for (int ks = 0; ks < 2; ++ks)
#pragma unroll
            for (int fm = 0; fm < FM; ++fm)
#pragma unroll
                for (int fn = 0; fn < 4; ++fn)
                    acc[fm][fn] = __builtin_amdgcn_mfma_f32_16x16x32_bf16(
                        a[fm][ks], bb[fn][ks], acc[fm][fn], 0, 0, 0);
        cur ^= 1;
    }

#pragma unroll
    for (int fm = 0; fm < FM; ++fm) {
#pragma unroll
        for (int fn = 0; fn < 4; ++fn) {
            int col = n0 + wc * 64 + fn * 16 + l15;
            float bv = bias[col];
            f32x4_t v = acc[fm][fn];
#pragma unroll
            for (int r = 0; r < 4; ++r) {
                int rowg = m0 + wr * WROWS + fm * 16 + l4 * 4 + r;
                float o = v[r] + bv;
                if (RELU) o = fmaxf(o, 0.f);
                if constexpr (OUT_BF16)
                    ((unsigned short*)out)[(size_t)rowg * N + col] = f2bf(o);
                else
                    ((float*)out)[(size_t)rowg * N + col] = o;
            }
        }
    }
}

// ---------------- launch ----------------

extern "C" void kernel_launch(void* const* d_in, const int* in_sizes, int n_in,
                              void* d_out, int out_size, void* d_ws, size_t ws_size,
                              hipStream_t stream) {
    const float* x_user  = (const float*)d_in[0];
    const float* x_movie = (const float*)d_in[1];
    const float* W1r_n = (const float*)d_in[2];
    const float* W1r_s = (const float*)d_in[3];
    const float* b1r   = (const float*)d_in[4];
    const float* W1b_n = (const float*)d_in[5];
    const float* W1b_s = (const float*)d_in[6];
    const float* b1b   = (const float*)d_in[7];
    const float* W2r_n = (const float*)d_in[8];
    const float* W2r_s = (const float*)d_in[9];
    const float* b2r   = (const float*)d_in[10];
    const float* W2b_n = (const float*)d_in[11];
    const float* W2b_s = (const float*)d_in[12];
    const float* b2b   = (const float*)d_in[13];
    const int* e0r_src = (const int*)d_in[14];
    const int* e0r_dst = (const int*)d_in[15];
    const int* e0b_src = (const int*)d_in[16];
    const int* e0b_dst = (const int*)d_in[17];
    const int* e1r_src = (const int*)d_in[18];
    const int* e1r_dst = (const int*)d_in[19];
    const int* e1b_src = (const int*)d_in[20];
    const int* e1b_dst = (const int*)d_in[21];

    // ---- workspace layout ----
    constexpr size_t MPAD = 40064;  // cD0 padded up for BM=128 tail
    char* w = (char*)d_ws;
    size_t o = 0;
    auto take = [&](size_t bytes) -> void* {
        void* p = w + o; o += (bytes + 255) & ~(size_t)255; return p;
    };
    unsigned short* h1m   = (unsigned short*)take(MPAD * cDH * 2);
    unsigned short* h1u   = (unsigned short*)take(MPAD * cDH * 2);
    unsigned short* aggR  = (unsigned short*)take(MPAD * cDIN * 2);
    unsigned short* aggB  = (unsigned short*)take(MPAD * cDIN * 2);
    unsigned short* agg2R = (unsigned short*)take((size_t)cD1 * cDH * 2);
    unsigned short* agg2B = (unsigned short*)take((size_t)cD1 * cDH * 2);
    unsigned short* wt    = (unsigned short*)take((size_t)8 * 131072 * 2);
    unsigned short* xub   = (unsigned short*)take((size_t)cS0 * cDIN * 2);
    unsigned short* xmb   = (unsigned short*)take((size_t)cS0 * cDIN * 2);
    int* deg_all = (int*)take((size_t)2 * NTOT * 4);   // deg + cur contiguous (one memset)
    int* cur_all = deg_all + NTOT;
    int* off_all = (int*)take((size_t)NTOT * 4);
    int* btot    = (int*)take(512);
    int* csr_all = (int*)take((size_t)ETOT * 4);
    if (ws_size < o) return;  // insufficient workspace: fail visibly

    const int* off0 = off_all;
    const int* off1 = off_all + P0;
    const int* off2 = off_all + 2 * P0;
    const int* off3 = off_all + 2 * P0 + P1;
    const int* csr0 = csr_all;
    const int* csr1 = csr_all + cE0;
    const int* csr2 = csr_all + 2 * cE0;
    const int* csr3 = csr_all + 2 * cE0 + cE1;

    float* out_u2 = (float*)d_out;
    float* out_m2 = (float*)d_out + (size_t)cD1 * cDOUT;

    // 1) zero deg+cur
    hipMemsetAsync(deg_all, 0, (size_t)2 * NTOT * 4, stream);
    // 2) fused front: cvt (dense, NT reads) | weight transpose | degree count
    WPtrs WP;
    WP.w[0] = W1r_s; WP.w[1] = W1r_n; WP.w[2] = W1b_s; WP.w[3] = W1b_n;
    WP.w[4] = W2r_s; WP.w[5] = W2r_n; WP.w[6] = W2b_s; WP.w[7] = W2b_n;
    k_front<<<NCVT_BLK + NWT_BLK + NDEG_BLK, 256, 0, stream>>>(
        x_user, x_movie, xub, xmb, WP, wt,
        e0r_dst, e0b_dst, e1r_dst, e1b_dst, deg_all);
    // 3-5) scans
    k_scanA<<<NBLK, 256, 0, stream>>>(deg_all, off_all, btot);
    k_scanB<<<1, 128, 0, stream>>>(btot);
    k_scanC<<<NBLK, 256, 0, stream>>>(off_all, btot);
    // 6) CSR fill
    k_fill_all<<<(ETOT + 255) / 256, 256, 0, stream>>>(
        e0r_src, e0r_dst, e0b_src, e0b_dst, e1r_src, e1r_dst, e1b_src, e1b_dst,
        off_all, cur_all, csr_all);

    // 7) layer-1 aggregation: rel0 'rates' src=user, rel1 'rated_by' src=movie
    k_agg2<cDIN><<<2 * (cD0 / 4), 256, 0, stream>>>(
        xub, off0, csr0, aggR, xmb, off1, csr1, aggB, cD0);
    // 8) layer-1 dual GEMM: [h1m | h1u], BM=128, mtiles=313 (tail rows padded)
    k_gemm2<128, cDIN, cDH, true, true><<<2 * 313 * (cDH / 128), 256, 0, stream>>>(
        xmb, aggR, wt + 0 * 131072, wt + 1 * 131072, b1r, h1m,
        xub, aggB, wt + 2 * 131072, wt + 3 * 131072, b1b, h1u, 313);

    // 9) layer-2 aggregation: rel0 src=u1(h1u), rel1 src=m1(h1m)
    k_agg2<cDH><<<2 * (cD1 / 4), 256, 0, stream>>>(
        h1u, off2, csr2, agg2R, h1m, off3, csr3, agg2B, cD1);
    // 10) layer-2 dual GEMM: [m2 | u2], BM=64, mtiles=128
    k_gemm2<64, cDH, cDOUT, false, false><<<2 * 128 * (cDOUT / 128), 256, 0, stream>>>(
        h1m, agg2R, wt + 4 * 131072, wt + 5 * 131072, b2r, out_m2,
        h1u, agg2B, wt + 6 * 131072, wt + 7 * 131072, b2b, out_u2, 128);
}

// Round 7
// 454.867 us; speedup vs baseline: 3.1232x; 1.0168x over previous
//
#include <hip/hip_runtime.h>
#include <stdint.h>

#define DEV_INLINE __device__ __forceinline__

constexpr int cS0 = 200000, cD0 = 40000, cD1 = 8192;
constexpr int cE0 = 640000, cE1 = 131072;
constexpr int cDIN = 256, cDH = 512, cDOUT = 256;

// padded per-relation node-region sizes (multiples of 1024; D1 regions get +1024 so off[n] exists)
constexpr int P0 = 40960, P1 = 9216;
constexpr int NTOT = 2 * P0 + 2 * P1;   // 100352
constexpr int NBLK = NTOT / 1024;       // 98
constexpr int ETOT = 2 * cE0 + 2 * cE1; // 1542144

// fused front kernel block partition
constexpr long QCVT = (long)cS0 * cDIN / 4 / 2;       // 6.4M float4: quarter of total cvt work
constexpr int NCVT_BLK = (int)(QCVT / 256);           // 25000 (4 float4 per thread, ILP)
constexpr int NWT_BLK  = 4096;                        // 8 * 131072 / 256
constexpr int NDEG_BLK = (ETOT + 255) / 256;          // 6024

typedef __attribute__((ext_vector_type(8))) short bf16x8_t;
typedef __attribute__((ext_vector_type(4))) float f32x4_t;

DEV_INLINE float bf2f(unsigned short u) {
    union { unsigned int i; float f; } x; x.i = ((unsigned int)u) << 16; return x.f;
}
DEV_INLINE unsigned short f2bf(float f) {
    union { float f; unsigned int i; } x; x.f = f;
    unsigned int r = x.i + 0x7FFF + ((x.i >> 16) & 1);
    return (unsigned short)(r >> 16);
}

DEV_INLINE void gload_lds16(const void* g, void* l) {
    __builtin_amdgcn_global_load_lds(
        (__attribute__((address_space(1))) void*)(uintptr_t)g,
        (__attribute__((address_space(3))) void*)(uintptr_t)l,
        16, 0, 0);
}

struct WPtrs { const float* w[8]; };

// ---------------- fused front: x->bf16 convert | weight transpose | degree count ----------------

__global__ __launch_bounds__(256) void k_front(
    const float* __restrict__ xu, const float* __restrict__ xm,
    unsigned short* __restrict__ ou, unsigned short* __restrict__ om,
    WPtrs W, unsigned short* __restrict__ wt,
    const int* __restrict__ d0, const int* __restrict__ d1,
    const int* __restrict__ d2, const int* __restrict__ d3,
    int* __restrict__ deg) {
    int b = blockIdx.x;
    if (b < NCVT_BLK) {
        // ILP-4: each thread converts 4 float4s (2 per table), all loads independent.
        long i = (long)b * 256 + threadIdx.x;     // float4 index in [0, QCVT)
        f32x4_t v0 = __builtin_nontemporal_load((const f32x4_t*)xu + i);
        f32x4_t v1 = __builtin_nontemporal_load((const f32x4_t*)xu + i + QCVT);
        f32x4_t v2 = __builtin_nontemporal_load((const f32x4_t*)xm + i);
        f32x4_t v3 = __builtin_nontemporal_load((const f32x4_t*)xm + i + QCVT);
        union { unsigned short us[4]; uint2 q; } pk;
        pk.us[0] = f2bf(v0.x); pk.us[1] = f2bf(v0.y); pk.us[2] = f2bf(v0.z); pk.us[3] = f2bf(v0.w);
        *(uint2*)(ou + i * 4) = pk.q;
        pk.us[0] = f2bf(v1.x); pk.us[1] = f2bf(v1.y); pk.us[2] = f2bf(v1.z); pk.us[3] = f2bf(v1.w);
        *(uint2*)(ou + (i + QCVT) * 4) = pk.q;
        pk.us[0] = f2bf(v2.x); pk.us[1] = f2bf(v2.y); pk.us[2] = f2bf(v2.z); pk.us[3] = f2bf(v2.w);
        *(uint2*)(om + i * 4) = pk.q;
        pk.us[0] = f2bf(v3.x); pk.us[1] = f2bf(v3.y); pk.us[2] = f2bf(v3.z); pk.us[3] = f2bf(v3.w);
        *(uint2*)(om + (i + QCVT) * 4) = pk.q;
        return;
    }
    b -= NCVT_BLK;
    if (b < NWT_BLK) {                            // W [K][N] fp32 -> Wt [N][K] bf16
        int idx = b * 256 + threadIdx.x;
        int slot = idx >> 17, e = idx & 131071;
        int K = slot < 4 ? cDIN : cDH;
        int N = slot < 4 ? cDH : cDOUT;
        int n = e / K, k = e % K;
        wt[idx] = f2bf(W.w[slot][(size_t)k * N + n]);
        return;
    }
    b -= NWT_BLK;
    int i = b * 256 + threadIdx.x;
    if (i >= ETOT) return;
    const int* dp; int base, noff;
    if (i < cE0)                { dp = d0; base = 0;             noff = 0; }
    else if (i < 2 * cE0)       { dp = d1; base = cE0;           noff = P0; }
    else if (i < 2 * cE0 + cE1) { dp = d2; base = 2 * cE0;       noff = 2 * P0; }
    else                        { dp = d3; base = 2 * cE0 + cE1; noff = 2 * P0 + P1; }
    atomicAdd(&deg[noff + dp[i - base]], 1);
}

// ---------------- CSR scan + fill ----------------

// per-1024-element block exclusive scan + block totals
__global__ __launch_bounds__(256) void k_scanA(const int* __restrict__ deg, int* __restrict__ off,
                                               int* __restrict__ btot) {
    __shared__ int buf[256];
    int t = threadIdx.x;
    long base = (long)blockIdx.x * 1024;
    int4 v = *(const int4*)(deg + base + t * 4);
    int s1 = v.x + v.y, s2 = s1 + v.z, ts = s2 + v.w;
    buf[t] = ts; __syncthreads();
    for (int o = 1; o < 256; o <<= 1) {
        int u = (t >= o) ? buf[t - o] : 0;
        __syncthreads(); buf[t] += u; __syncthreads();
    }
    int ex = buf[t] - ts;
    int4 w; w.x = ex; w.y = ex + v.x; w.z = ex + s1; w.w = ex + s2;
    *(int4*)(off + base + t * 4) = w;
    if (t == 255) btot[blockIdx.x] = buf[255];
}

// segmented exclusive scan of the 98 block totals (segments = 4 node regions)
__global__ void k_scanB(int* __restrict__ bt) {
    __shared__ int buf[128];
    __shared__ int seg[128];
    int t = threadIdx.x;
    int s = (t >= 89) ? 3 : (t >= 80) ? 2 : (t >= 40) ? 1 : 0;
    int v = (t < NBLK) ? bt[t] : 0;
    buf[t] = v; seg[t] = s; __syncthreads();
    for (int o = 1; o < 128; o <<= 1) {
        int u = 0;
        if (t >= o && seg[t - o] == s) u = buf[t - o];
        __syncthreads(); buf[t] += u; __syncthreads();
    }
    if (t < NBLK) bt[t] = buf[t] - v;   // exclusive within segment
}

__global__ __launch_bounds__(256) void k_scanC(int* __restrict__ off, const int* __restrict__ bt) {
    int t = threadIdx.x;
    long base = (long)blockIdx.x * 1024;
    int bo = bt[blockIdx.x];
    int4 v = *(int4*)(off + base + t * 4);
    v.x += bo; v.y += bo; v.z += bo; v.w += bo;
    *(int4*)(off + base + t * 4) = v;
}

__global__ __launch_bounds__(256) void k_fill_all(
    const int* __restrict__ s0, const int* __restrict__ d0, const int* __restrict__ s1, const int* __restrict__ d1,
    const int* __restrict__ s2, const int* __restrict__ d2, const int* __restrict__ s3, const int* __restrict__ d3,
    const int* __restrict__ off, int* __restrict__ cur, int* __restrict__ csr) {
    int i = blockIdx.x * 256 + threadIdx.x;
    if (i >= ETOT) return;
    const int* sp; const int* dp; int base, noff, cbase;
    if (i < cE0)                { sp = s0; dp = d0; base = 0;             noff = 0;           cbase = 0; }
    else if (i < 2 * cE0)       { sp = s1; dp = d1; base = cE0;           noff = P0;          cbase = cE0; }
    else if (i < 2 * cE0 + cE1) { sp = s2; dp = d2; base = 2 * cE0;       noff = 2 * P0;      cbase = 2 * cE0; }
    else                        { sp = s3; dp = d3; base = 2 * cE0 + cE1; noff = 2 * P0 + P1; cbase = 2 * cE0 + cE1; }
    int li = i - base;
    int d = dp[li];
    int p = atomicAdd(&cur[noff + d], 1);
    csr[cbase + off[noff + d] + p] = sp[li];
}

// ---------------- merged mean aggregation (2 relations per launch), bf16 in/out ----------------
// High-MLP: 16B/lane row coverage, 8-deep unroll.
//   K=256: half-wave (32 lanes) per edge slot, 2 edge slots/wave, x8 unroll -> 16 loads in flight.
//   K=512: full wave per edge, x8 unroll -> 8 loads in flight.

template <int K>
__global__ __launch_bounds__(256) void k_agg2(
    const unsigned short* __restrict__ x0, const int* __restrict__ off0, const int* __restrict__ csr0,
    unsigned short* __restrict__ o0,
    const unsigned short* __restrict__ x1, const int* __restrict__ off1, const int* __restrict__ csr1,
    unsigned short* __restrict__ o1, int ndst) {
    constexpr bool HALF = (K == 256);
    constexpr int ESTEP = HALF ? 2 : 1;     // edges per unroll slot
    constexpr int U = 8;
    int nb = ndst / 4;
    int b = blockIdx.x;
    const unsigned short* xs; const int* off; const int* csr; unsigned short* out;
    if (b >= nb) { xs = x1; off = off1; csr = csr1; out = o1; b -= nb; }
    else         { xs = x0; off = off0; csr = csr0; out = o0; }
    int lane = threadIdx.x & 63;
    int d = b * 4 + (threadIdx.x >> 6);
    int elane = HALF ? (lane & 31) : lane;  // 16B-granule index within row
    int eslot = HALF ? (lane >> 5) : 0;

    float acc[8];
#pragma unroll
    for (int i = 0; i < 8; i++) acc[i] = 0.f;
    int p0 = off[d], p1 = off[d + 1];

    for (int p = p0; p < p1; p += U * ESTEP) {
        int idx[U];
#pragma unroll
        for (int u = 0; u < U; ++u) {
            int q = p + u * ESTEP + eslot;
            idx[u] = (q < p1) ? csr[q] : -1;
        }
#pragma unroll
        for (int u = 0; u < U; ++u) {
            if (idx[u] >= 0) {
                uint4 v = *(const uint4*)(xs + (size_t)idx[u] * K + elane * 8);
                const unsigned short* us = (const unsigned short*)&v;
#pragma unroll
                for (int i = 0; i < 8; ++i) acc[i] += bf2f(us[i]);
            }
        }
    }
    if constexpr (HALF) {
#pragma unroll
        for (int i = 0; i < 8; ++i) acc[i] += __shfl_xor(acc[i], 32);
    }
    int dg = p1 - p0;
    float sc = 1.0f / (float)(dg > 1 ? dg : 1);
    union { unsigned short us[8]; uint4 v4; } pk;
#pragma unroll
    for (int i = 0; i < 8; i++) pk.us[i] = f2bf(acc[i] * sc);
    if (!HALF || lane < 32)
        *(uint4*)(out + (size_t)d * K + (size_t)elane * 8) = pk.v4;
}

// ---------------- fused SAGE GEMM (MFMA bf16), 2 relations per launch ----------------
// out = act( Aself@Wself + Aagg@Wneigh + bias ); K concat as 2 segments of KSEG.
// BMxBN tile (BN=128), BK=64; 4 waves 2x2; wave tile (BM/2)x64.
// LDS rows of 64 bf16 (128B = 8 x 16B chunks); chunk-XOR swizzle phys = logical ^ (row&7),
// applied on the *global source* address (LDS dest stays linear for global_load_lds).
// Block index XCD-swizzled (grid must be a multiple of 8).

template <int BM, int KSEG, int N, bool OUT_BF16, bool RELU>
__global__ __launch_bounds__(256) void k_gemm2(
    const unsigned short* __restrict__ aself0, const unsigned short* __restrict__ aagg0,
    const unsigned short* __restrict__ bts0, const unsigned short* __restrict__ btn0,
    const float* __restrict__ bias0, void* __restrict__ out0,
    const unsigned short* __restrict__ aself1, const unsigned short* __restrict__ aagg1,
    const unsigned short* __restrict__ bts1, const unsigned short* __restrict__ btn1,
    const float* __restrict__ bias1, void* __restrict__ out1,
    int mtiles) {
    constexpr int BN = 128, BK = 64;
    constexpr int H = KSEG / BK, NSTEP = 2 * H;
    constexpr int WROWS = BM / 2, FM = WROWS / 16;   // frags per wave (row dim)
    constexpr int AIT = BM / 32;                     // A staging iterations
    __shared__ __align__(16) unsigned short As[2][BM * BK];
    __shared__ __align__(16) unsigned short Bs[2][BN * BK];

    const int tiles_n = N / BN;
    const int gpr = mtiles * tiles_n;
    // XCD-aware swizzle (gridDim.x % 8 == 0): contiguous logical chunk per XCD
    int b = blockIdx.x;
    {
        int cpx = gridDim.x >> 3;
        b = (b & 7) * cpx + (b >> 3);
    }
    const unsigned short *aself, *aagg, *bts, *btn; const float* bias; void* out;
    if (b >= gpr) { b -= gpr; aself = aself1; aagg = aagg1; bts = bts1; btn = btn1; bias = bias1; out = out1; }
    else          {           aself = aself0; aagg = aagg0; bts = bts0; btn = btn0; bias = bias0; out = out0; }
    const int m0 = (b / tiles_n) * BM;
    const int n0 = (b % tiles_n) * BN;
    const int t = threadIdx.x, lane = t & 63, wave = t >> 6;
    const int wr = wave >> 1, wc = wave & 1;
    const int l15 = lane & 15, l4 = lane >> 4;

    f32x4_t acc[FM][4];
    const f32x4_t zero = {0.f, 0.f, 0.f, 0.f};
#pragma unroll
    for (int i = 0; i < FM; i++)
#pragma unroll
        for (int j = 0; j < 4; j++) acc[i][j] = zero;

    auto stage = [&](int buf, int s) {
        const int seg = (s >= H) ? 1 : 0;
        const int k0 = (s - seg * H) * BK;
        const unsigned short* A = seg ? aagg : aself;
        const unsigned short* B = seg ? btn : bts;
#pragma unroll
        for (int it = 0; it < AIT; ++it) {          // A: BM rows x 8 chunks
            int c = it * 256 + t;
            int row = c >> 3;
            int lch = (c & 7) ^ (row & 7);
            gload_lds16(A + (size_t)(m0 + row) * KSEG + k0 + lch * 8,
                        (char*)&As[buf][0] + (it * 256 + wave * 64) * 16);
        }
#pragma unroll
        for (int it = 0; it < 4; ++it) {            // B: 128 rows x 8 chunks
            int c = it * 256 + t;
            int row = c >> 3;
            int lch = (c & 7) ^ (row & 7);
            gload_lds16(B + (size_t)(n0 + row) * KSEG + k0 + lch * 8,
                        (char*)&Bs[buf][0] + (it * 256 + wave * 64) * 16);
        }
    };

    int cur = 0;
    stage(0, 0);
    for (int s = 0; s < NSTEP; ++s) {
        __syncthreads();                  // drains vmcnt -> buf[cur] staged; prior reads done
        if (s + 1 < NSTEP) stage(cur ^ 1, s + 1);
        const char* Ab = (const char*)&As[cur][0];
        const char* Bb = (const char*)&Bs[cur][0];
        bf16x8_t a[FM][2], bb[4][2];
#pragma unroll
        for (int fm = 0; fm < FM; ++fm) {
            int row = wr * WROWS + fm * 16 + l15;
#pragma unroll
            for (int ks = 0; ks < 2; ++ks) {
                int pc = (ks * 4 + l4) ^ (row & 7);
                a[fm][ks] = *(const bf16x8_t*)(Ab + row * 128 + pc * 16);
            }
        }
#pragma unroll
        for (int fn = 0; fn < 4; ++fn) {
            int row = wc * 64 + fn * 16 + l15;
#pragma unroll
            for (int ks = 0; ks < 2; ++ks) {
                int pc = (ks * 4 + l4) ^ (row & 7);
                bb[fn][ks] = *(const bf16x8_t*)(Bb + row * 128 + pc * 16);
            }
        }
#pragma unroll
        for (int ks = 0; ks < 2; ++ks)
#pragma unroll
            for (int fm = 0; fm < FM; ++fm)
#pragma unroll
                for (int fn = 0; fn < 4; ++fn)
                    acc[fm][fn] = __builtin_amdgcn_mfma_f32_16x16x32_bf16(
                        a[fm][ks], bb[fn][ks], acc[fm][fn], 0, 0, 0);
        cur ^= 1;
    }

#pragma unroll
    for (int fm = 0; fm < FM; ++fm) {
#pragma unroll
        for (int fn = 0; fn < 4; ++fn) {
            int col = n0 + wc * 64 + fn * 16 + l15;
            float bv = bias[col];
            f32x4_t v = acc[fm][fn];
#pragma unroll
            for (int r = 0; r < 4; ++r) {
                int rowg = m0 + wr * WROWS + fm * 16 + l4 * 4 + r;
                float o = v[r] + bv;
                if (RELU) o = fmaxf(o, 0.f);
                if constexpr (OUT_BF16)
                    ((unsigned short*)out)[(size_t)rowg * N + col] = f2bf(o);
                else
                    ((float*)out)[(size_t)rowg * N + col] = o;
            }
        }
    }
}

// ---------------- launch ----------------

extern "C" void kernel_launch(void* const* d_in, const int* in_sizes, int n_in,
                              void* d_out, int out_size, void* d_ws, size_t ws_size,
                              hipStream_t stream) {
    const float* x_user  = (const float*)d_in[0];
    const float* x_movie = (const float*)d_in[1];
    const float* W1r_n = (const float*)d_in[2];
    const float* W1r_s = (const float*)d_in[3];
    const float* b1r   = (const float*)d_in[4];
    const float* W1b_n = (const float*)d_in[5];
    const float* W1b_s = (const float*)d_in[6];
    const float* b1b   = (const float*)d_in[7];
    const float* W2r_n = (const float*)d_in[8];
    const float* W2r_s = (const float*)d_in[9];
    const float* b2r   = (const float*)d_in[10];
    const float* W2b_n = (const float*)d_in[11];
    const float* W2b_s = (const float*)d_in[12];
    const float* b2b   = (const float*)d_in[13];
    const int* e0r_src = (const int*)d_in[14];
    const int* e0r_dst = (const int*)d_in[15];
    const int* e0b_src = (const int*)d_in[16];
    const int* e0b_dst = (const int*)d_in[17];
    const int* e1r_src = (const int*)d_in[18];
    const int* e1r_dst = (const int*)d_in[19];
    const int* e1b_src = (const int*)d_in[20];
    const int* e1b_dst = (const int*)d_in[21];

    // ---- workspace layout ----
    constexpr size_t MPAD = 40064;  // cD0 padded up for BM=128 tail
    char* w = (char*)d_ws;
    size_t o = 0;
    auto take = [&](size_t bytes) -> void* {
        void* p = w + o; o += (bytes + 255) & ~(size_t)255; return p;
    };
    unsigned short* h1m   = (unsigned short*)take(MPAD * cDH * 2);
    unsigned short* h1u   = (unsigned short*)take(MPAD * cDH * 2);
    unsigned short* aggR  = (unsigned short*)take(MPAD * cDIN * 2);
    unsigned short* aggB  = (unsigned short*)take(MPAD * cDIN * 2);
    unsigned short* agg2R = (unsigned short*)take((size_t)cD1 * cDH * 2);
    unsigned short* agg2B = (unsigned short*)take((size_t)cD1 * cDH * 2);
    unsigned short* wt    = (unsigned short*)take((size_t)8 * 131072 * 2);
    unsigned short* xub   = (unsigned short*)take((size_t)cS0 * cDIN * 2);
    unsigned short* xmb   = (unsigned short*)take((size_t)cS0 * cDIN * 2);
    int* deg_all = (int*)take((size_t)2 * NTOT * 4);   // deg + cur contiguous (one memset)
    int* cur_all = deg_all + NTOT;
    int* off_all = (int*)take((size_t)NTOT * 4);
    int* btot    = (int*)take(512);
    int* csr_all = (int*)take((size_t)ETOT * 4);
    if (ws_size < o) return;  // insufficient workspace: fail visibly

    const int* off0 = off_all;
    const int* off1 = off_all + P0;
    const int* off2 = off_all + 2 * P0;
    const int* off3 = off_all + 2 * P0 + P1;
    const int* csr0 = csr_all;
    const int* csr1 = csr_all + cE0;
    const int* csr2 = csr_all + 2 * cE0;
    const int* csr3 = csr_all + 2 * cE0 + cE1;

    float* out_u2 = (float*)d_out;
    float* out_m2 = (float*)d_out + (size_t)cD1 * cDOUT;

    // 1) zero deg+cur
    hipMemsetAsync(deg_all, 0, (size_t)2 * NTOT * 4, stream);
    // 2) fused front: cvt (ILP-4, NT reads) | weight transpose | degree count
    WPtrs WP;
    WP.w[0] = W1r_s; WP.w[1] = W1r_n; WP.w[2] = W1b_s; WP.w[3] = W1b_n;
    WP.w[4] = W2r_s; WP.w[5] = W2r_n; WP.w[6] = W2b_s; WP.w[7] = W2b_n;
    k_front<<<NCVT_BLK + NWT_BLK + NDEG_BLK, 256, 0, stream>>>(
        x_user, x_movie, xub, xmb, WP, wt,
        e0r_dst, e0b_dst, e1r_dst, e1b_dst, deg_all);
    // 3-5) scans
    k_scanA<<<NBLK, 256, 0, stream>>>(deg_all, off_all, btot);
    k_scanB<<<1, 128, 0, stream>>>(btot);
    k_scanC<<<NBLK, 256, 0, stream>>>(off_all, btot);
    // 6) CSR fill
    k_fill_all<<<(ETOT + 255) / 256, 256, 0, stream>>>(
        e0r_src, e0r_dst, e0b_src, e0b_dst, e1r_src, e1r_dst, e1b_src, e1b_dst,
        off_all, cur_all, csr_all);

    // 7) layer-1 aggregation: rel0 'rates' src=user, rel1 'rated_by' src=movie
    k_agg2<cDIN><<<2 * (cD0 / 4), 256, 0, stream>>>(
        xub, off0, csr0, aggR, xmb, off1, csr1, aggB, cD0);
    // 8) layer-1 dual GEMM: [h1m | h1u], BM=128, mtiles=313 (tail rows padded)
    k_gemm2<128, cDIN, cDH, true, true><<<2 * 313 * (cDH / 128), 256, 0, stream>>>(
        xmb, aggR, wt + 0 * 131072, wt + 1 * 131072, b1r, h1m,
        xub, aggB, wt + 2 * 131072, wt + 3 * 131072, b1b, h1u, 313);

    // 9) layer-2 aggregation: rel0 src=u1(h1u), rel1 src=m1(h1m)
    k_agg2<cDH><<<2 * (cD1 / 4), 256, 0, stream>>>(
        h1u, off2, csr2, agg2R, h1m, off3, csr3, agg2B, cD1);
    // 10) layer-2 dual GEMM: [m2 | u2], BM=64, mtiles=128
    k_gemm2<64, cDH, cDOUT, false, false><<<2 * 128 * (cDOUT / 128), 256, 0, stream>>>(
        h1m, agg2R, wt + 4 * 131072, wt + 5 * 131072, b2r, out_m2,
        h1u, agg2B, wt + 6 * 131072, wt + 7 * 131072, b2b, out_u2, 128);
}